// Round 2
// baseline (378.883 us; speedup 1.0000x reference)
//
#include <hip/hip_runtime.h>
#include <stdint.h>
#include <math.h>

typedef unsigned int u32;
typedef unsigned long long u64;

#define BB 8
#define AA 19206
#define CCH 91
#define NCLS 90
#define KSEL 256
#define MAXDET 100
#define NROWS (BB*NCLS)      // 720
#define NFLAT (NCLS*MAXDET)  // 9000
#define IOU_T 0.6f
#define NSLICE 4
#define SL 4802              // 4*4802 = 19208 >= 19206, even, 8B-aligned slices
#define CAP 2048             // candidate capacity per row

// ---------------- decode (+ zero per-row candidate counters) ----------------
__global__ void __launch_bounds__(256) k_decode(const float* __restrict__ enc,
    const float* __restrict__ anch, float* __restrict__ dec, u32* __restrict__ gcnt) {
  if (blockIdx.x == 0) {
    for (int j = threadIdx.x; j < NROWS; j += 256) gcnt[j] = 0u;
  }
  int i = blockIdx.x * 256 + threadIdx.x;
  if (i >= BB * AA) return;
  int a = i % AA;
  float4 e  = ((const float4*)enc)[i];
  float4 an = ((const float4*)anch)[a];
  float ty = e.x / 10.0f, tx = e.y / 10.0f, th = e.z / 5.0f, tw = e.w / 5.0f;
  float yc = ty * an.z + an.x;
  float xc = tx * an.w + an.y;
  float h  = expf(th) * an.z;
  float w  = expf(tw) * an.w;
  float4 o;
  o.x = yc - h * 0.5f; o.y = xc - w * 0.5f; o.z = yc + h * 0.5f; o.w = xc + w * 0.5f;
  ((float4*)dec)[i] = o;
}

// ---------------- sigmoid + transpose (per batch-chunk) ----------------
#define ATILE 64
__global__ void __launch_bounds__(256) k_sigT(const float* __restrict__ logits,
                                              float* __restrict__ sc, int b0) {
  __shared__ __align__(16) float tile[ATILE * CCH];  // 23.3 KB
  int bl = blockIdx.y;            // local batch within chunk
  int b  = b0 + bl;               // global batch
  int a0 = blockIdx.x * ATILE;
  int nt = AA - a0; if (nt > ATILE) nt = ATILE;
  int nload = nt * CCH;           // even (nt*91: nt=64 or 6)
  const float* src = logits + ((size_t)b * AA + a0) * CCH;   // 8B aligned
  const float2* s2 = (const float2*)src;
  int n2 = nload >> 1;
  for (int i = threadIdx.x; i < n2; i += 256) ((float2*)tile)[i] = s2[i];
  __syncthreads();
  for (int j = threadIdx.x; j < ATILE * NCLS; j += 256) {
    int c  = j >> 6;       // 0..89  (whole wave shares c -> coalesced store)
    int ai = j & 63;
    if (ai < nt) {
      float x = tile[ai * CCH + (c + 1)];
      float s = 1.0f / (1.0f + expf(-x));
      sc[((size_t)bl * NCLS + c) * AA + a0 + ai] = s;
    }
  }
}

// ---------------- bitonic sorts (block of 256 threads) ----------------
__device__ inline void bitonic_u64_asc(u64* a, int n, int tid) {
  for (int k = 2; k <= n; k <<= 1) {
    for (int j = k >> 1; j > 0; j >>= 1) {
      for (int i = tid; i < n; i += 256) {
        int l = i ^ j;
        if (l > i) {
          u64 x = a[i], y = a[l];
          bool asc = ((i & k) == 0);
          if ((x > y) == asc) { a[i] = y; a[l] = x; }
        }
      }
      __syncthreads();
    }
  }
}
__device__ inline void bitonic_u32_asc(u32* a, int n, int tid) {
  for (int k = 2; k <= n; k <<= 1) {
    for (int j = k >> 1; j > 0; j >>= 1) {
      for (int i = tid; i < n; i += 256) {
        int l = i ^ j;
        if (l > i) {
          u32 x = a[i], y = a[l];
          bool asc = ((i & k) == 0);
          if ((x > y) == asc) { a[i] = y; a[l] = x; }
        }
      }
      __syncthreads();
    }
  }
}

// ---------------- exact radix select (rank kwant, descending) ----------------
// Wave-aggregates the u==0 hot bin (flat scores contain thousands of zeros).
template<typename F>
__device__ inline void radix_select(F getv, int n, int kwant,
    u32* hist, u32* suf, int* sh2, int tid,
    u32& V_out, int& GT_out, int& r_out) {
  int r = kwant; u32 V = 0; int GT = 0;
  for (int lvl = 0; lvl < 3; lvl++) {
    int shift = (lvl == 0) ? 19 : ((lvl == 1) ? 8 : 0);
    int nbins = (lvl == 2) ? 256 : 2048;
    for (int i = tid; i < nbins; i += 256) hist[i] = 0;
    __syncthreads();
    for (int idx = tid; idx < n; idx += 256) {
      u32 u = __float_as_uint(getv(idx));
      bool ok = (lvl == 0) || (lvl == 1 ? ((u >> 19) == (V >> 19))
                                        : ((u >> 8)  == (V >> 8)));
      u64 zm = __ballot(ok && u == 0u);
      if (ok) {
        if (u == 0u) {
          if ((int)(threadIdx.x & 63) == (int)(__ffsll((long long)zm) - 1))
            atomicAdd(&hist[0], (u32)__popcll(zm));
        } else {
          atomicAdd(&hist[(u >> shift) & (u32)(nbins - 1)], 1u);
        }
      }
    }
    __syncthreads();
    int G = nbins >> 8;
    u32 ps = 0;
    for (int g = 0; g < G; g++) ps += hist[tid * G + g];
    suf[tid] = ps;
    __syncthreads();
    for (int off = 1; off < 256; off <<= 1) {
      u32 v = (tid + off < 256) ? suf[tid + off] : 0u;
      __syncthreads();
      suf[tid] += v;
      __syncthreads();
    }
    u32 sufnext = (tid < 255) ? suf[tid + 1] : 0u;
    if (suf[tid] >= (u32)r && sufnext < (u32)r) {
      u32 cum = sufnext; int kb = tid * G;
      for (int bin = tid * G + G - 1; bin >= tid * G; bin--) {
        cum += hist[bin];
        if (cum >= (u32)r) { kb = bin; break; }
      }
      sh2[0] = kb;
      sh2[1] = (int)(cum - hist[kb]);
    }
    __syncthreads();
    int kb = sh2[0], gt = sh2[1];
    r -= gt; GT += gt; V |= ((u32)kb) << shift;
    __syncthreads();
  }
  V_out = V; GT_out = GT; r_out = r;
}

// ---------------- sliced single-pass candidate select ----------------
// grid: (NSLICE, rows_in_chunk). Keeps every element whose 11-bit prefix bin is
// >= the slice-local bin containing local rank-256 -> superset of row top-256.
__global__ void __launch_bounds__(256) k_select(const float* __restrict__ sc,
    u64* __restrict__ cand, u32* __restrict__ gcnt, int row0) {
  __shared__ u32 hist[2048];
  __shared__ u32 suf[256];
  __shared__ int shBs;
  int rl = blockIdx.y;           // local row within chunk
  int row = row0 + rl;           // global row
  int s = blockIdx.x, tid = threadIdx.x;
  const float* base = sc + (size_t)rl * AA + (size_t)s * SL;
  int n = AA - s * SL; if (n > SL) n = SL;   // 4802/4802/4802/4800 (even)
  int n2 = n >> 1;
  const float2* b2 = (const float2*)base;    // 8B aligned
  for (int i = tid; i < 2048; i += 256) hist[i] = 0;
  __syncthreads();
  for (int i = tid; i < n2; i += 256) {
    float2 v = b2[i];
    atomicAdd(&hist[__float_as_uint(v.x) >> 19], 1u);   // positive floats: <2048
    atomicAdd(&hist[__float_as_uint(v.y) >> 19], 1u);
  }
  __syncthreads();
  u32 ps = 0;
#pragma unroll
  for (int g = 0; g < 8; g++) ps += hist[tid * 8 + g];
  suf[tid] = ps;
  __syncthreads();
  for (int off = 1; off < 256; off <<= 1) {
    u32 v = (tid + off < 256) ? suf[tid + off] : 0u;
    __syncthreads();
    suf[tid] += v;
    __syncthreads();
  }
  u32 sufnext = (tid < 255) ? suf[tid + 1] : 0u;
  if (suf[tid] >= (u32)KSEL && sufnext < (u32)KSEL) {
    u32 cum = sufnext; int kb = tid * 8;
    for (int bin = tid * 8 + 7; bin >= tid * 8; bin--) {
      cum += hist[bin];
      if (cum >= (u32)KSEL) { kb = bin; break; }
    }
    shBs = kb;
  }
  __syncthreads();
  u32 Bs = (u32)shBs;
  for (int i = tid; i < n2; i += 256) {
    float2 v = b2[i];                       // L2-hot second read
    u32 ux = __float_as_uint(v.x), uy = __float_as_uint(v.y);
    if ((ux >> 19) >= Bs) {
      u32 p = atomicAdd(&gcnt[row], 1u);
      if (p < CAP) cand[(size_t)row * CAP + p] =
        ((u64)ux << 32) | (u32)(~(u32)(s * SL + 2 * i));
    }
    if ((uy >> 19) >= Bs) {
      u32 p = atomicAdd(&gcnt[row], 1u);
      if (p < CAP) cand[(size_t)row * CAP + p] =
        ((u64)uy << 32) | (u32)(~(u32)(s * SL + 2 * i + 1));
    }
  }
}

// ---------------- finalize top-256 per row: sort candidates ----------------
__global__ void __launch_bounds__(256) k_T(const u64* __restrict__ cand,
    const u32* __restrict__ gcnt, float* __restrict__ tks, int* __restrict__ tki) {
  __shared__ u64 a[CAP];   // 16 KB
  int row = blockIdx.x, tid = threadIdx.x;
  int n = (int)gcnt[row]; if (n > CAP) n = CAP;   // n >= 4*256 guaranteed
  int np2 = 1024; while (np2 < n) np2 <<= 1;     // 1024 or 2048
  for (int i = tid; i < n; i += 256) a[i] = cand[(size_t)row * CAP + i];
  for (int i = n + tid; i < np2; i += 256) a[i] = 0;  // pad keys sort low
  __syncthreads();
  bitonic_u64_asc(a, np2, tid);
  for (int j = tid; j < KSEL; j += 256) {
    u64 kk = a[np2 - 1 - j];
    tks[(size_t)row * KSEL + j] = __uint_as_float((u32)(kk >> 32));
    tki[(size_t)row * KSEL + j] = (int)(~(u32)kk);
  }
}

// ---------------- fallback: direct strided top-256 (small ws only) ----------
__global__ void __launch_bounds__(256) k_topk_direct(const float* __restrict__ src,
    float* __restrict__ tks, int* __restrict__ tki) {
  __shared__ u32 hist[2048];
  __shared__ u32 suf[256];
  __shared__ int sh2[2];
  __shared__ u64 sel[KSEL];
  __shared__ u32 tie[512];
  __shared__ int cgt, ctie;
  int row = blockIdx.x, tid = threadIdx.x;
  int b = row / NCLS, c = row % NCLS;
  const float* base = src + (size_t)b * AA * CCH + (c + 1);
  auto getv = [&](int i) -> float {
    float x = base[(size_t)i * CCH]; return 1.0f / (1.0f + expf(-x));
  };
  u32 V; int GT, r;
  radix_select(getv, AA, KSEL, hist, suf, sh2, tid, V, GT, r);
  if (tid == 0) { cgt = 0; ctie = 0; }
  __syncthreads();
  for (int i = tid; i < AA; i += 256) {
    u32 u = __float_as_uint(getv(i));
    if (u > V) {
      int p = atomicAdd(&cgt, 1);
      sel[p] = ((u64)u << 32) | (u32)(~(u32)i);
    } else if (u == V) {
      int p = atomicAdd(&ctie, 1);
      if (p < 512) tie[p] = (u32)i;
    }
  }
  __syncthreads();
  int nt = ctie < 512 ? ctie : 512;
  for (int i = tid + nt; i < 512; i += 256) tie[i] = 0xFFFFFFFFu;
  __syncthreads();
  bitonic_u32_asc(tie, 512, tid);
  for (int i = tid; i < r; i += 256)
    sel[GT + i] = ((u64)V << 32) | (u32)(~tie[i]);
  __syncthreads();
  bitonic_u64_asc(sel, KSEL, tid);
  for (int j = tid; j < KSEL; j += 256) {
    u64 kk = sel[KSEL - 1 - j];
    tks[(size_t)row * KSEL + j] = __uint_as_float((u32)(kk >> 32));
    tki[(size_t)row * KSEL + j] = (int)(~(u32)kk);
  }
}

// ---------------- NMS: one wave per (b,c) row ----------------
__global__ void __launch_bounds__(256) k_nms(const float* __restrict__ dec,
    const float* __restrict__ tks, const int* __restrict__ tki,
    float* __restrict__ flat_s, float* __restrict__ flat_b) {
  __shared__ float4 bxs[4][KSEL];   // 16 KB
  int wid = threadIdx.x >> 6, lane = threadIdx.x & 63;
  int row = blockIdx.x * 4 + wid;
  int b = row / NCLS, c = row % NCLS;
  float  s[4]; float4 bx[4]; float ar[4];
  for (int k = 0; k < 4; k++) {
    int j = lane + 64 * k;
    s[k] = tks[(size_t)row * KSEL + j];
    int ai = tki[(size_t)row * KSEL + j];
    float4 bb = ((const float4*)dec)[(size_t)b * AA + ai];
    bx[k] = bb;
    ar[k] = (bb.z - bb.x) * (bb.w - bb.y);
    bxs[wid][j] = bb;
  }
  __syncthreads();
  for (int d = 0; d < MAXDET; d++) {
    u64 best = 0;
    for (int k = 0; k < 4; k++) {
      u32 ub = __float_as_uint(s[k]);
      u32 mu = (ub & 0x80000000u) ? ~ub : (ub | 0x80000000u);  // monotone map
      best = max(best, (((u64)mu << 32) | (u32)(255 - (lane + 64 * k))));
    }
    for (int off = 1; off < 64; off <<= 1) {
      u64 o = __shfl_xor(best, off);
      best = max(best, o);
    }
    int i  = 255 - (int)(best & 0xFFu);
    u32 mu = (u32)(best >> 32);
    u32 ub = (mu & 0x80000000u) ? (mu & 0x7FFFFFFFu) : ~mu;
    float val = __uint_as_float(ub);
    bool keep = val > 0.0f;
    float4 bi = bxs[wid][i];                 // broadcast read
    float ia  = (bi.z - bi.x) * (bi.w - bi.y);
    if (lane == 0) {
      size_t fo = (size_t)b * NFLAT + (size_t)c * MAXDET + d;
      flat_s[fo] = keep ? val : 0.0f;
      float4 ob;
      if (keep) ob = bi; else { ob.x = ob.y = ob.z = ob.w = 0.0f; }
      ((float4*)flat_b)[fo] = ob;
    }
    for (int k = 0; k < 4; k++) {
      float ty = fmaxf(bi.x, bx[k].x), tx = fmaxf(bi.y, bx[k].y);
      float by = fminf(bi.z, bx[k].z), bxx = fminf(bi.w, bx[k].w);
      float wy = fmaxf(by - ty, 0.0f), wx = fmaxf(bxx - tx, 0.0f);
      float inter = wy * wx;
      float un = ia + ar[k] - inter;
      float iou = inter / fmaxf(un, 1e-8f);
      if (iou >= IOU_T) s[k] = -1.0f;
    }
  }
}

// ---------------- final per-batch top-100 (LDS-staged) ----------------
__global__ void __launch_bounds__(256) k_final(const float* __restrict__ flat_s,
    const float* __restrict__ flat_b, float* __restrict__ out) {
  __shared__ float sdata[NFLAT];   // 36 KB
  __shared__ u32 hist[2048];
  __shared__ u32 suf[256];
  __shared__ int sh2[2];
  __shared__ u64 sel[128];
  __shared__ u32 tie[256];
  __shared__ int cgt, ctie;
  int b = blockIdx.x, tid = threadIdx.x;
  const float2* d2 = (const float2*)(flat_s + (size_t)b * NFLAT);
  for (int i = tid; i < NFLAT / 2; i += 256) {
    float2 v = d2[i];
    sdata[2 * i] = v.x; sdata[2 * i + 1] = v.y;
  }
  __syncthreads();
  auto getv = [&](int i) -> float { return sdata[i]; };
  u32 V; int GT, r;
  radix_select(getv, NFLAT, MAXDET, hist, suf, sh2, tid, V, GT, r);
  if (tid == 0) { cgt = 0; ctie = 0; }
  __syncthreads();
  for (int i = tid; i < NFLAT; i += 256) {
    u32 u = __float_as_uint(sdata[i]);
    if (u > V) {
      int p = atomicAdd(&cgt, 1);
      sel[p] = ((u64)u << 32) | (u32)(~(u32)i);
    } else if (u == V) {
      int p = atomicAdd(&ctie, 1);
      if (p < 256) tie[p] = (u32)i;
    }
  }
  __syncthreads();
  int nt = ctie < 256 ? ctie : 256;
  for (int i = tid + nt; i < 256; i += 256) tie[i] = 0xFFFFFFFFu;
  __syncthreads();
  bitonic_u32_asc(tie, 256, tid);
  for (int i = tid; i < r; i += 256)
    sel[GT + i] = ((u64)V << 32) | (u32)(~tie[i]);
  for (int i = MAXDET + tid; i < 128; i += 256) sel[i] = 0;
  __syncthreads();
  bitonic_u64_asc(sel, 128, tid);
  for (int d = tid; d < MAXDET; d += 256) {
    u64 kk = sel[127 - d];
    u32 u  = (u32)(kk >> 32);
    int fi = (int)(~(u32)kk);
    float4 bb = ((const float4*)flat_b)[(size_t)b * NFLAT + fi];
    float* o = out + ((size_t)b * MAXDET + d) * 6;
    o[0] = bb.x; o[1] = bb.y; o[2] = bb.z; o[3] = bb.w;
    o[4] = (float)(fi / 100 + 1);
    o[5] = __uint_as_float(u);
  }
}

// ---------------- launch ----------------
extern "C" void kernel_launch(void* const* d_in, const int* in_sizes, int n_in,
                              void* d_out, int out_size, void* d_ws, size_t ws_size,
                              hipStream_t stream) {
  const float* enc    = (const float*)d_in[0];
  const float* logits = (const float*)d_in[1];
  const float* anch   = (const float*)d_in[2];
  float* out = (float*)d_out;
  char* ws = (char*)d_ws;

  size_t off = 0;
  auto alloc = [&](size_t bytes) {
    size_t o = off;
    off += (bytes + 255) & ~(size_t)255;
    return o;
  };
  size_t o_dec  = alloc((size_t)BB * AA * 16);        // decoded boxes (float4)
  size_t o_tks  = alloc((size_t)NROWS * KSEL * 4);
  size_t o_tki  = alloc((size_t)NROWS * KSEL * 4);
  size_t o_gcnt = alloc((size_t)NROWS * 4);
  size_t o_cand = alloc((size_t)NROWS * CAP * 8);     // 11.8 MB
  // flat_s/flat_b alias the candidate buffer (cand dead after k_T, nms after)
  size_t o_fls = o_cand;
  size_t o_flb = o_cand + (((size_t)BB * NFLAT * 4 + 255) & ~(size_t)255);
  size_t need_base = off;
  size_t o_sc = off;                                   // chunked sc goes here
  size_t per_batch_sc = ((size_t)NCLS * AA * 4 + 255) & ~(size_t)255; // 6.92 MB

  // pick largest batch-chunk that fits the workspace
  int CB = 0;
  for (int cb = BB; cb >= 1; cb >>= 1) {
    if (ws_size >= need_base + (size_t)cb * per_batch_sc) { CB = cb; break; }
  }

  float* dec = (float*)(ws + o_dec);
  float* tks = (float*)(ws + o_tks);
  int*   tki = (int*)  (ws + o_tki);
  u32*   gcnt= (u32*)  (ws + o_gcnt);
  u64*   cand= (u64*)  (ws + o_cand);
  float* fls = (float*)(ws + o_fls);
  float* flb = (float*)(ws + o_flb);
  float* scp = (float*)(ws + o_sc);

  hipLaunchKernelGGL(k_decode, dim3((BB * AA + 255) / 256), dim3(256), 0, stream,
                     enc, anch, dec, gcnt);
  if (CB > 0) {
    for (int b0 = 0; b0 < BB; b0 += CB) {
      hipLaunchKernelGGL(k_sigT, dim3((AA + ATILE - 1) / ATILE, CB), dim3(256), 0,
                         stream, logits, scp, b0);
      hipLaunchKernelGGL(k_select, dim3(NSLICE, NCLS * CB), dim3(256), 0, stream,
                         scp, cand, gcnt, b0 * NCLS);
    }
    hipLaunchKernelGGL(k_T, dim3(NROWS), dim3(256), 0, stream,
                       cand, gcnt, tks, tki);
  } else {
    hipLaunchKernelGGL(k_topk_direct, dim3(NROWS), dim3(256), 0, stream,
                       logits, tks, tki);
  }
  hipLaunchKernelGGL(k_nms, dim3(NROWS / 4), dim3(256), 0, stream,
                     dec, tks, tki, fls, flb);
  hipLaunchKernelGGL(k_final, dim3(BB), dim3(256), 0, stream,
                     fls, flb, out);
}

// Round 3
// 193.409 us; speedup vs baseline: 1.9590x; 1.9590x over previous
//
#include <hip/hip_runtime.h>
#include <stdint.h>
#include <math.h>

typedef unsigned int u32;
typedef unsigned long long u64;

#define BB 8
#define AA 19206
#define CCH 91
#define NCLS 90
#define KSEL 256
#define MAXDET 100
#define NROWS (BB*NCLS)      // 720
#define NFLAT (NCLS*MAXDET)  // 9000
#define IOU_T 0.6f

// ---------------- decode ----------------
__global__ void __launch_bounds__(256) k_decode(const float* __restrict__ enc,
    const float* __restrict__ anch, float* __restrict__ dec) {
  int i = blockIdx.x * 256 + threadIdx.x;
  if (i >= BB * AA) return;
  int a = i % AA;
  float4 e  = ((const float4*)enc)[i];
  float4 an = ((const float4*)anch)[a];
  float ty = e.x / 10.0f, tx = e.y / 10.0f, th = e.z / 5.0f, tw = e.w / 5.0f;
  float yc = ty * an.z + an.x;
  float xc = tx * an.w + an.y;
  float h  = expf(th) * an.z;
  float w  = expf(tw) * an.w;
  float4 o;
  o.x = yc - h * 0.5f; o.y = xc - w * 0.5f; o.z = yc + h * 0.5f; o.w = xc + w * 0.5f;
  ((float4*)dec)[i] = o;
}

// ---------------- sigmoid + transpose (per batch-chunk) ----------------
#define ATILE 64
__global__ void __launch_bounds__(256) k_sigT(const float* __restrict__ logits,
                                              float* __restrict__ sc, int b0) {
  __shared__ __align__(16) float tile[ATILE * CCH];  // 23.3 KB
  int bl = blockIdx.y;            // local batch within chunk
  int b  = b0 + bl;               // global batch
  int a0 = blockIdx.x * ATILE;
  int nt = AA - a0; if (nt > ATILE) nt = ATILE;
  int nload = nt * CCH;           // even
  const float* src = logits + ((size_t)b * AA + a0) * CCH;   // 8B aligned
  const float2* s2 = (const float2*)src;
  int n2 = nload >> 1;
  for (int i = threadIdx.x; i < n2; i += 256) ((float2*)tile)[i] = s2[i];
  __syncthreads();
  for (int j = threadIdx.x; j < ATILE * NCLS; j += 256) {
    int c  = j >> 6;       // whole wave shares c -> coalesced store
    int ai = j & 63;
    if (ai < nt) {
      float x = tile[ai * CCH + (c + 1)];
      float s = 1.0f / (1.0f + expf(-x));
      sc[((size_t)bl * NCLS + c) * AA + a0 + ai] = s;
    }
  }
}

// ---------------- per-row top-256: stage row in LDS, arith bins, sort ------
__global__ void __launch_bounds__(512) k_row(const float* __restrict__ sc,
    float* __restrict__ tks, int* __restrict__ tki, int row0) {
  __shared__ __align__(16) float rowv[AA + 2];  // 76.8 KB
  __shared__ u32 hist[256];
  __shared__ u32 suf[256];
  __shared__ u64 cand[512];
  __shared__ int shBs, ctr;
  int rl  = blockIdx.x;
  int row = row0 + rl;
  int tid = threadIdx.x;
  const float2* src = (const float2*)(sc + (size_t)rl * AA);  // AA even
  if (tid < 256) hist[tid] = 0;
  if (tid == 0) ctr = 0;
  __syncthreads();
  for (int i = tid; i < AA / 2; i += 512) {
    float2 v = src[i];
    ((float2*)rowv)[i] = v;
    int b0 = min(255, (int)(v.x * 256.0f));   // scores in (0,1]; monotone bin
    int b1 = min(255, (int)(v.y * 256.0f));
    atomicAdd(&hist[b0], 1u);
    atomicAdd(&hist[b1], 1u);
  }
  __syncthreads();
  if (tid < 256) suf[tid] = hist[tid];
  __syncthreads();
  for (int off = 1; off < 256; off <<= 1) {
    u32 v = 0;
    if (tid < 256 && tid + off < 256) v = suf[tid + off];
    __syncthreads();
    if (tid < 256) suf[tid] += v;
    __syncthreads();
  }
  if (tid < 256) {
    u32 nxt = (tid < 255) ? suf[tid + 1] : 0u;
    if (suf[tid] >= (u32)KSEL && nxt < (u32)KSEL) shBs = tid;
  }
  __syncthreads();
  int Bs = shBs;
  // compact candidates (bin >= Bs) with wave-aggregated LDS append
  for (int i = tid; i < AA; i += 512) {
    float v = rowv[i];
    bool p = min(255, (int)(v * 256.0f)) >= Bs;
    u64 m = __ballot(p);
    if (p) {
      int lane = tid & 63;
      int leader = (int)(__ffsll((long long)m) - 1);
      int base = 0;
      if (lane == leader) base = atomicAdd(&ctr, (int)__popcll(m));
      base = __shfl(base, leader);
      int pos = base + (int)__popcll(m & ((1ull << lane) - 1ull));
      if (pos < 512)
        cand[pos] = ((u64)__float_as_uint(v) << 32) | (u32)(~(u32)i);
    }
  }
  __syncthreads();
  int n = ctr < 512 ? ctr : 512;
  for (int i = n + tid; i < 512; i += 512) cand[i] = 0;  // pad sorts low
  __syncthreads();
  // bitonic sort 512 ascending, 1 element per thread
  for (int k = 2; k <= 512; k <<= 1) {
    for (int j = k >> 1; j > 0; j >>= 1) {
      int l = tid ^ j;
      if (l > tid) {
        u64 x = cand[tid], y = cand[l];
        bool asc = ((tid & k) == 0);
        if ((x > y) == asc) { cand[tid] = y; cand[l] = x; }
      }
      __syncthreads();
    }
  }
  if (tid < KSEL) {
    u64 kk = cand[511 - tid];
    tks[(size_t)row * KSEL + tid] = __uint_as_float((u32)(kk >> 32));
    tki[(size_t)row * KSEL + tid] = (int)(~(u32)kk);
  }
}

// ---------------- bitonic sorts (block of 256 threads) ----------------
__device__ inline void bitonic_u64_asc(u64* a, int n, int tid) {
  for (int k = 2; k <= n; k <<= 1) {
    for (int j = k >> 1; j > 0; j >>= 1) {
      for (int i = tid; i < n; i += 256) {
        int l = i ^ j;
        if (l > i) {
          u64 x = a[i], y = a[l];
          bool asc = ((i & k) == 0);
          if ((x > y) == asc) { a[i] = y; a[l] = x; }
        }
      }
      __syncthreads();
    }
  }
}
__device__ inline void bitonic_u32_asc(u32* a, int n, int tid) {
  for (int k = 2; k <= n; k <<= 1) {
    for (int j = k >> 1; j > 0; j >>= 1) {
      for (int i = tid; i < n; i += 256) {
        int l = i ^ j;
        if (l > i) {
          u32 x = a[i], y = a[l];
          bool asc = ((i & k) == 0);
          if ((x > y) == asc) { a[i] = y; a[l] = x; }
        }
      }
      __syncthreads();
    }
  }
}

// ---------------- exact radix select (rank kwant, descending) ----------------
template<typename F>
__device__ inline void radix_select(F getv, int n, int kwant,
    u32* hist, u32* suf, int* sh2, int tid,
    u32& V_out, int& GT_out, int& r_out) {
  int r = kwant; u32 V = 0; int GT = 0;
  for (int lvl = 0; lvl < 3; lvl++) {
    int shift = (lvl == 0) ? 19 : ((lvl == 1) ? 8 : 0);
    int nbins = (lvl == 2) ? 256 : 2048;
    for (int i = tid; i < nbins; i += 256) hist[i] = 0;
    __syncthreads();
    for (int idx = tid; idx < n; idx += 256) {
      u32 u = __float_as_uint(getv(idx));
      bool ok = (lvl == 0) || (lvl == 1 ? ((u >> 19) == (V >> 19))
                                        : ((u >> 8)  == (V >> 8)));
      u64 zm = __ballot(ok && u == 0u);
      if (ok) {
        if (u == 0u) {
          if ((int)(threadIdx.x & 63) == (int)(__ffsll((long long)zm) - 1))
            atomicAdd(&hist[0], (u32)__popcll(zm));
        } else {
          atomicAdd(&hist[(u >> shift) & (u32)(nbins - 1)], 1u);
        }
      }
    }
    __syncthreads();
    int G = nbins >> 8;
    u32 ps = 0;
    for (int g = 0; g < G; g++) ps += hist[tid * G + g];
    suf[tid] = ps;
    __syncthreads();
    for (int off = 1; off < 256; off <<= 1) {
      u32 v = (tid + off < 256) ? suf[tid + off] : 0u;
      __syncthreads();
      suf[tid] += v;
      __syncthreads();
    }
    u32 sufnext = (tid < 255) ? suf[tid + 1] : 0u;
    if (suf[tid] >= (u32)r && sufnext < (u32)r) {
      u32 cum = sufnext; int kb = tid * G;
      for (int bin = tid * G + G - 1; bin >= tid * G; bin--) {
        cum += hist[bin];
        if (cum >= (u32)r) { kb = bin; break; }
      }
      sh2[0] = kb;
      sh2[1] = (int)(cum - hist[kb]);
    }
    __syncthreads();
    int kb = sh2[0], gt = sh2[1];
    r -= gt; GT += gt; V |= ((u32)kb) << shift;
    __syncthreads();
  }
  V_out = V; GT_out = GT; r_out = r;
}

// ---------------- fallback: direct strided top-256 (small ws only) ----------
__global__ void __launch_bounds__(256) k_topk_direct(const float* __restrict__ src,
    float* __restrict__ tks, int* __restrict__ tki) {
  __shared__ u32 hist[2048];
  __shared__ u32 suf[256];
  __shared__ int sh2[2];
  __shared__ u64 sel[KSEL];
  __shared__ u32 tie[512];
  __shared__ int cgt, ctie;
  int row = blockIdx.x, tid = threadIdx.x;
  int b = row / NCLS, c = row % NCLS;
  const float* base = src + (size_t)b * AA * CCH + (c + 1);
  auto getv = [&](int i) -> float {
    float x = base[(size_t)i * CCH]; return 1.0f / (1.0f + expf(-x));
  };
  u32 V; int GT, r;
  radix_select(getv, AA, KSEL, hist, suf, sh2, tid, V, GT, r);
  if (tid == 0) { cgt = 0; ctie = 0; }
  __syncthreads();
  for (int i = tid; i < AA; i += 256) {
    u32 u = __float_as_uint(getv(i));
    if (u > V) {
      int p = atomicAdd(&cgt, 1);
      sel[p] = ((u64)u << 32) | (u32)(~(u32)i);
    } else if (u == V) {
      int p = atomicAdd(&ctie, 1);
      if (p < 512) tie[p] = (u32)i;
    }
  }
  __syncthreads();
  int nt = ctie < 512 ? ctie : 512;
  for (int i = tid + nt; i < 512; i += 256) tie[i] = 0xFFFFFFFFu;
  __syncthreads();
  bitonic_u32_asc(tie, 512, tid);
  for (int i = tid; i < r; i += 256)
    sel[GT + i] = ((u64)V << 32) | (u32)(~tie[i]);
  __syncthreads();
  bitonic_u64_asc(sel, KSEL, tid);
  for (int j = tid; j < KSEL; j += 256) {
    u64 kk = sel[KSEL - 1 - j];
    tks[(size_t)row * KSEL + j] = __uint_as_float((u32)(kk >> 32));
    tki[(size_t)row * KSEL + j] = (int)(~(u32)kk);
  }
}

// ---------------- NMS: one wave per (b,c) row ----------------
__global__ void __launch_bounds__(256) k_nms(const float* __restrict__ dec,
    const float* __restrict__ tks, const int* __restrict__ tki,
    float* __restrict__ flat_s, float* __restrict__ flat_b) {
  __shared__ float4 bxs[4][KSEL];   // 16 KB
  int wid = threadIdx.x >> 6, lane = threadIdx.x & 63;
  int row = blockIdx.x * 4 + wid;
  int b = row / NCLS, c = row % NCLS;
  float  s[4]; float4 bx[4]; float ar[4];
  for (int k = 0; k < 4; k++) {
    int j = lane + 64 * k;
    s[k] = tks[(size_t)row * KSEL + j];
    int ai = tki[(size_t)row * KSEL + j];
    float4 bb = ((const float4*)dec)[(size_t)b * AA + ai];
    bx[k] = bb;
    ar[k] = (bb.z - bb.x) * (bb.w - bb.y);
    bxs[wid][j] = bb;
  }
  __syncthreads();
  for (int d = 0; d < MAXDET; d++) {
    u64 best = 0;
    for (int k = 0; k < 4; k++) {
      u32 ub = __float_as_uint(s[k]);
      u32 mu = (ub & 0x80000000u) ? ~ub : (ub | 0x80000000u);  // monotone map
      best = max(best, (((u64)mu << 32) | (u32)(255 - (lane + 64 * k))));
    }
    for (int off = 1; off < 64; off <<= 1) {
      u64 o = __shfl_xor(best, off);
      best = max(best, o);
    }
    int i  = 255 - (int)(best & 0xFFu);
    u32 mu = (u32)(best >> 32);
    u32 ub = (mu & 0x80000000u) ? (mu & 0x7FFFFFFFu) : ~mu;
    float val = __uint_as_float(ub);
    bool keep = val > 0.0f;
    float4 bi = bxs[wid][i];                 // broadcast read
    float ia  = (bi.z - bi.x) * (bi.w - bi.y);
    if (lane == 0) {
      size_t fo = (size_t)b * NFLAT + (size_t)c * MAXDET + d;
      flat_s[fo] = keep ? val : 0.0f;
      float4 ob;
      if (keep) ob = bi; else { ob.x = ob.y = ob.z = ob.w = 0.0f; }
      ((float4*)flat_b)[fo] = ob;
    }
    for (int k = 0; k < 4; k++) {
      float ty = fmaxf(bi.x, bx[k].x), tx = fmaxf(bi.y, bx[k].y);
      float by = fminf(bi.z, bx[k].z), bxx = fminf(bi.w, bx[k].w);
      float wy = fmaxf(by - ty, 0.0f), wx = fmaxf(bxx - tx, 0.0f);
      float inter = wy * wx;
      float un = ia + ar[k] - inter;
      float iou = inter / fmaxf(un, 1e-8f);
      if (iou >= IOU_T) s[k] = -1.0f;
    }
  }
}

// ---------------- final per-batch top-100 (LDS-staged) ----------------
__global__ void __launch_bounds__(256) k_final(const float* __restrict__ flat_s,
    const float* __restrict__ flat_b, float* __restrict__ out) {
  __shared__ float sdata[NFLAT];   // 36 KB
  __shared__ u32 hist[2048];
  __shared__ u32 suf[256];
  __shared__ int sh2[2];
  __shared__ u64 sel[128];
  __shared__ u32 tie[256];
  __shared__ int cgt, ctie;
  int b = blockIdx.x, tid = threadIdx.x;
  const float2* d2 = (const float2*)(flat_s + (size_t)b * NFLAT);
  for (int i = tid; i < NFLAT / 2; i += 256) {
    float2 v = d2[i];
    sdata[2 * i] = v.x; sdata[2 * i + 1] = v.y;
  }
  __syncthreads();
  auto getv = [&](int i) -> float { return sdata[i]; };
  u32 V; int GT, r;
  radix_select(getv, NFLAT, MAXDET, hist, suf, sh2, tid, V, GT, r);
  if (tid == 0) { cgt = 0; ctie = 0; }
  __syncthreads();
  for (int i = tid; i < NFLAT; i += 256) {
    u32 u = __float_as_uint(sdata[i]);
    if (u > V) {
      int p = atomicAdd(&cgt, 1);
      sel[p] = ((u64)u << 32) | (u32)(~(u32)i);
    } else if (u == V) {
      int p = atomicAdd(&ctie, 1);
      if (p < 256) tie[p] = (u32)i;
    }
  }
  __syncthreads();
  int nt = ctie < 256 ? ctie : 256;
  for (int i = tid + nt; i < 256; i += 256) tie[i] = 0xFFFFFFFFu;
  __syncthreads();
  bitonic_u32_asc(tie, 256, tid);
  for (int i = tid; i < r; i += 256)
    sel[GT + i] = ((u64)V << 32) | (u32)(~tie[i]);
  for (int i = MAXDET + tid; i < 128; i += 256) sel[i] = 0;
  __syncthreads();
  bitonic_u64_asc(sel, 128, tid);
  for (int d = tid; d < MAXDET; d += 256) {
    u64 kk = sel[127 - d];
    u32 u  = (u32)(kk >> 32);
    int fi = (int)(~(u32)kk);
    float4 bb = ((const float4*)flat_b)[(size_t)b * NFLAT + fi];
    float* o = out + ((size_t)b * MAXDET + d) * 6;
    o[0] = bb.x; o[1] = bb.y; o[2] = bb.z; o[3] = bb.w;
    o[4] = (float)(fi / 100 + 1);
    o[5] = __uint_as_float(u);
  }
}

// ---------------- launch ----------------
extern "C" void kernel_launch(void* const* d_in, const int* in_sizes, int n_in,
                              void* d_out, int out_size, void* d_ws, size_t ws_size,
                              hipStream_t stream) {
  const float* enc    = (const float*)d_in[0];
  const float* logits = (const float*)d_in[1];
  const float* anch   = (const float*)d_in[2];
  float* out = (float*)d_out;
  char* ws = (char*)d_ws;

  size_t off = 0;
  auto alloc = [&](size_t bytes) {
    size_t o = off;
    off += (bytes + 255) & ~(size_t)255;
    return o;
  };
  size_t o_dec  = alloc((size_t)BB * AA * 16);        // decoded boxes (float4)
  size_t o_tks  = alloc((size_t)NROWS * KSEL * 4);
  size_t o_tki  = alloc((size_t)NROWS * KSEL * 4);
  size_t o_fls  = alloc((size_t)BB * NFLAT * 4);
  size_t o_flb  = alloc((size_t)BB * NFLAT * 16);
  size_t need_base = off;
  size_t o_sc = off;                                   // chunked sc goes here
  size_t per_batch_sc = ((size_t)NCLS * AA * 4 + 255) & ~(size_t)255; // 6.92 MB

  int CB = 0;
  for (int cb = BB; cb >= 1; cb >>= 1) {
    if (ws_size >= need_base + (size_t)cb * per_batch_sc) { CB = cb; break; }
  }

  float* dec = (float*)(ws + o_dec);
  float* tks = (float*)(ws + o_tks);
  int*   tki = (int*)  (ws + o_tki);
  float* fls = (float*)(ws + o_fls);
  float* flb = (float*)(ws + o_flb);
  float* scp = (float*)(ws + o_sc);

  hipLaunchKernelGGL(k_decode, dim3((BB * AA + 255) / 256), dim3(256), 0, stream,
                     enc, anch, dec);
  if (CB > 0) {
    for (int b0 = 0; b0 < BB; b0 += CB) {
      hipLaunchKernelGGL(k_sigT, dim3((AA + ATILE - 1) / ATILE, CB), dim3(256), 0,
                         stream, logits, scp, b0);
      hipLaunchKernelGGL(k_row, dim3(NCLS * CB), dim3(512), 0, stream,
                         scp, tks, tki, b0 * NCLS);
    }
  } else {
    hipLaunchKernelGGL(k_topk_direct, dim3(NROWS), dim3(256), 0, stream,
                       logits, tks, tki);
  }
  hipLaunchKernelGGL(k_nms, dim3(NROWS / 4), dim3(256), 0, stream,
                     dec, tks, tki, fls, flb);
  hipLaunchKernelGGL(k_final, dim3(BB), dim3(256), 0, stream,
                     fls, flb, out);
}

// Round 4
// 161.710 us; speedup vs baseline: 2.3430x; 1.1960x over previous
//
#include <hip/hip_runtime.h>
#include <stdint.h>
#include <math.h>

typedef unsigned int u32;
typedef unsigned long long u64;

#define BB 8
#define AA 19206
#define CCH 91
#define NCLS 90
#define KSEL 256
#define MAXDET 100
#define NROWS (BB*NCLS)      // 720
#define NFLAT (NCLS*MAXDET)  // 9000
#define IOU_T 0.6f

// ---------------- decode ----------------
__global__ void __launch_bounds__(256) k_decode(const float* __restrict__ enc,
    const float* __restrict__ anch, float* __restrict__ dec) {
  int i = blockIdx.x * 256 + threadIdx.x;
  if (i >= BB * AA) return;
  int a = i % AA;
  float4 e  = ((const float4*)enc)[i];
  float4 an = ((const float4*)anch)[a];
  float ty = e.x / 10.0f, tx = e.y / 10.0f, th = e.z / 5.0f, tw = e.w / 5.0f;
  float yc = ty * an.z + an.x;
  float xc = tx * an.w + an.y;
  float h  = expf(th) * an.z;
  float w  = expf(tw) * an.w;
  float4 o;
  o.x = yc - h * 0.5f; o.y = xc - w * 0.5f; o.z = yc + h * 0.5f; o.w = xc + w * 0.5f;
  ((float4*)dec)[i] = o;
}

// ---------------- sigmoid + transpose (per batch-chunk) ----------------
#define ATILE 64
__global__ void __launch_bounds__(256) k_sigT(const float* __restrict__ logits,
                                              float* __restrict__ sc, int b0) {
  __shared__ __align__(16) float tile[ATILE * CCH];  // 23.3 KB
  int bl = blockIdx.y;            // local batch within chunk
  int b  = b0 + bl;               // global batch
  int a0 = blockIdx.x * ATILE;
  int nt = AA - a0; if (nt > ATILE) nt = ATILE;
  int nload = nt * CCH;           // even
  const float* src = logits + ((size_t)b * AA + a0) * CCH;   // 8B aligned
  const float2* s2 = (const float2*)src;
  int n2 = nload >> 1;
  for (int i = threadIdx.x; i < n2; i += 256) ((float2*)tile)[i] = s2[i];
  __syncthreads();
  for (int j = threadIdx.x; j < ATILE * NCLS; j += 256) {
    int c  = j >> 6;       // whole wave shares c -> coalesced store
    int ai = j & 63;
    if (ai < nt) {
      float x = tile[ai * CCH + (c + 1)];
      float s = 1.0f / (1.0f + expf(-x));
      sc[((size_t)bl * NCLS + c) * AA + a0 + ai] = s;
    }
  }
}

// ---------------- per-row top-256: 2 global passes (L3-hot), small LDS ------
__global__ void __launch_bounds__(512) k_row(const float* __restrict__ sc,
    float* __restrict__ tks, int* __restrict__ tki, int row0) {
  __shared__ u32 hist[256];
  __shared__ u32 suf[256];
  __shared__ u64 cand[512];
  __shared__ int shBs, ctr;
  int rl  = blockIdx.x;
  int row = row0 + rl;
  int tid = threadIdx.x;
  const float2* src = (const float2*)(sc + (size_t)rl * AA);  // AA even
  if (tid < 256) hist[tid] = 0;
  if (tid == 0) ctr = 0;
  __syncthreads();
  for (int i = tid; i < AA / 2; i += 512) {
    float2 v = src[i];
    atomicAdd(&hist[min(255, (int)(v.x * 256.0f))], 1u);  // monotone bin
    atomicAdd(&hist[min(255, (int)(v.y * 256.0f))], 1u);
  }
  __syncthreads();
  if (tid < 256) suf[tid] = hist[tid];
  __syncthreads();
  for (int off = 1; off < 256; off <<= 1) {
    u32 v = 0;
    if (tid < 256 && tid + off < 256) v = suf[tid + off];
    __syncthreads();
    if (tid < 256) suf[tid] += v;
    __syncthreads();
  }
  if (tid < 256) {
    u32 nxt = (tid < 255) ? suf[tid + 1] : 0u;
    if (suf[tid] >= (u32)KSEL && nxt < (u32)KSEL) shBs = tid;
  }
  __syncthreads();
  int Bs = shBs;
  int lane = tid & 63;
  // pass 2: L2/L3-hot re-read, wave-aggregated LDS append of bins >= Bs
  for (int i = tid; i < AA / 2; i += 512) {
    float2 v = src[i];
    {
      bool p = min(255, (int)(v.x * 256.0f)) >= Bs;
      u64 m = __ballot(p);
      if (p) {
        int leader = (int)(__ffsll((long long)m) - 1);
        int base = 0;
        if (lane == leader) base = atomicAdd(&ctr, (int)__popcll(m));
        base = __shfl(base, leader);
        int pos = base + (int)__popcll(m & ((1ull << lane) - 1ull));
        if (pos < 512)
          cand[pos] = ((u64)__float_as_uint(v.x) << 32) | (u32)(~(u32)(2 * i));
      }
    }
    {
      bool p = min(255, (int)(v.y * 256.0f)) >= Bs;
      u64 m = __ballot(p);
      if (p) {
        int leader = (int)(__ffsll((long long)m) - 1);
        int base = 0;
        if (lane == leader) base = atomicAdd(&ctr, (int)__popcll(m));
        base = __shfl(base, leader);
        int pos = base + (int)__popcll(m & ((1ull << lane) - 1ull));
        if (pos < 512)
          cand[pos] = ((u64)__float_as_uint(v.y) << 32) | (u32)(~(u32)(2 * i + 1));
      }
    }
  }
  __syncthreads();
  int n = ctr < 512 ? ctr : 512;
  for (int i = n + tid; i < 512; i += 512) cand[i] = 0;  // pad sorts low
  __syncthreads();
  // bitonic sort 512 ascending, 1 element per thread
  for (int k = 2; k <= 512; k <<= 1) {
    for (int j = k >> 1; j > 0; j >>= 1) {
      int l = tid ^ j;
      if (l > tid) {
        u64 x = cand[tid], y = cand[l];
        bool asc = ((tid & k) == 0);
        if ((x > y) == asc) { cand[tid] = y; cand[l] = x; }
      }
      __syncthreads();
    }
  }
  if (tid < KSEL) {
    u64 kk = cand[511 - tid];
    tks[(size_t)row * KSEL + tid] = __uint_as_float((u32)(kk >> 32));
    tki[(size_t)row * KSEL + tid] = (int)(~(u32)kk);
  }
}

// ---------------- bitonic sorts (block of 256 threads) ----------------
__device__ inline void bitonic_u64_asc(u64* a, int n, int tid) {
  for (int k = 2; k <= n; k <<= 1) {
    for (int j = k >> 1; j > 0; j >>= 1) {
      for (int i = tid; i < n; i += 256) {
        int l = i ^ j;
        if (l > i) {
          u64 x = a[i], y = a[l];
          bool asc = ((i & k) == 0);
          if ((x > y) == asc) { a[i] = y; a[l] = x; }
        }
      }
      __syncthreads();
    }
  }
}
__device__ inline void bitonic_u32_asc(u32* a, int n, int tid) {
  for (int k = 2; k <= n; k <<= 1) {
    for (int j = k >> 1; j > 0; j >>= 1) {
      for (int i = tid; i < n; i += 256) {
        int l = i ^ j;
        if (l > i) {
          u32 x = a[i], y = a[l];
          bool asc = ((i & k) == 0);
          if ((x > y) == asc) { a[i] = y; a[l] = x; }
        }
      }
      __syncthreads();
    }
  }
}

// ---------------- exact radix select (rank kwant, descending) ----------------
template<typename F>
__device__ inline void radix_select(F getv, int n, int kwant,
    u32* hist, u32* suf, int* sh2, int tid,
    u32& V_out, int& GT_out, int& r_out) {
  int r = kwant; u32 V = 0; int GT = 0;
  for (int lvl = 0; lvl < 3; lvl++) {
    int shift = (lvl == 0) ? 19 : ((lvl == 1) ? 8 : 0);
    int nbins = (lvl == 2) ? 256 : 2048;
    for (int i = tid; i < nbins; i += 256) hist[i] = 0;
    __syncthreads();
    for (int idx = tid; idx < n; idx += 256) {
      u32 u = __float_as_uint(getv(idx));
      bool ok = (lvl == 0) || (lvl == 1 ? ((u >> 19) == (V >> 19))
                                        : ((u >> 8)  == (V >> 8)));
      u64 zm = __ballot(ok && u == 0u);
      if (ok) {
        if (u == 0u) {
          if ((int)(threadIdx.x & 63) == (int)(__ffsll((long long)zm) - 1))
            atomicAdd(&hist[0], (u32)__popcll(zm));
        } else {
          atomicAdd(&hist[(u >> shift) & (u32)(nbins - 1)], 1u);
        }
      }
    }
    __syncthreads();
    int G = nbins >> 8;
    u32 ps = 0;
    for (int g = 0; g < G; g++) ps += hist[tid * G + g];
    suf[tid] = ps;
    __syncthreads();
    for (int off = 1; off < 256; off <<= 1) {
      u32 v = (tid + off < 256) ? suf[tid + off] : 0u;
      __syncthreads();
      suf[tid] += v;
      __syncthreads();
    }
    u32 sufnext = (tid < 255) ? suf[tid + 1] : 0u;
    if (suf[tid] >= (u32)r && sufnext < (u32)r) {
      u32 cum = sufnext; int kb = tid * G;
      for (int bin = tid * G + G - 1; bin >= tid * G; bin--) {
        cum += hist[bin];
        if (cum >= (u32)r) { kb = bin; break; }
      }
      sh2[0] = kb;
      sh2[1] = (int)(cum - hist[kb]);
    }
    __syncthreads();
    int kb = sh2[0], gt = sh2[1];
    r -= gt; GT += gt; V |= ((u32)kb) << shift;
    __syncthreads();
  }
  V_out = V; GT_out = GT; r_out = r;
}

// ---------------- fallback: direct strided top-256 (small ws only) ----------
__global__ void __launch_bounds__(256) k_topk_direct(const float* __restrict__ src,
    float* __restrict__ tks, int* __restrict__ tki) {
  __shared__ u32 hist[2048];
  __shared__ u32 suf[256];
  __shared__ int sh2[2];
  __shared__ u64 sel[KSEL];
  __shared__ u32 tie[512];
  __shared__ int cgt, ctie;
  int row = blockIdx.x, tid = threadIdx.x;
  int b = row / NCLS, c = row % NCLS;
  const float* base = src + (size_t)b * AA * CCH + (c + 1);
  auto getv = [&](int i) -> float {
    float x = base[(size_t)i * CCH]; return 1.0f / (1.0f + expf(-x));
  };
  u32 V; int GT, r;
  radix_select(getv, AA, KSEL, hist, suf, sh2, tid, V, GT, r);
  if (tid == 0) { cgt = 0; ctie = 0; }
  __syncthreads();
  for (int i = tid; i < AA; i += 256) {
    u32 u = __float_as_uint(getv(i));
    if (u > V) {
      int p = atomicAdd(&cgt, 1);
      sel[p] = ((u64)u << 32) | (u32)(~(u32)i);
    } else if (u == V) {
      int p = atomicAdd(&ctie, 1);
      if (p < 512) tie[p] = (u32)i;
    }
  }
  __syncthreads();
  int nt = ctie < 512 ? ctie : 512;
  for (int i = tid + nt; i < 512; i += 256) tie[i] = 0xFFFFFFFFu;
  __syncthreads();
  bitonic_u32_asc(tie, 512, tid);
  for (int i = tid; i < r; i += 256)
    sel[GT + i] = ((u64)V << 32) | (u32)(~tie[i]);
  __syncthreads();
  bitonic_u64_asc(sel, KSEL, tid);
  for (int j = tid; j < KSEL; j += 256) {
    u64 kk = sel[KSEL - 1 - j];
    tks[(size_t)row * KSEL + j] = __uint_as_float((u32)(kk >> 32));
    tki[(size_t)row * KSEL + j] = (int)(~(u32)kk);
  }
}

// ---------------- NMS: one wave per (b,c) row ----------------
__global__ void __launch_bounds__(256) k_nms(const float* __restrict__ dec,
    const float* __restrict__ tks, const int* __restrict__ tki,
    float* __restrict__ flat_s, float* __restrict__ flat_b) {
  __shared__ float4 bxs[4][KSEL];   // 16 KB
  int wid = threadIdx.x >> 6, lane = threadIdx.x & 63;
  int row = blockIdx.x * 4 + wid;
  int b = row / NCLS, c = row % NCLS;
  float  s[4]; float4 bx[4]; float ar[4];
  for (int k = 0; k < 4; k++) {
    int j = lane + 64 * k;
    s[k] = tks[(size_t)row * KSEL + j];
    int ai = tki[(size_t)row * KSEL + j];
    float4 bb = ((const float4*)dec)[(size_t)b * AA + ai];
    bx[k] = bb;
    ar[k] = (bb.z - bb.x) * (bb.w - bb.y);
    bxs[wid][j] = bb;
  }
  __syncthreads();
  for (int d = 0; d < MAXDET; d++) {
    u64 best = 0;
    for (int k = 0; k < 4; k++) {
      u32 ub = __float_as_uint(s[k]);
      u32 mu = (ub & 0x80000000u) ? ~ub : (ub | 0x80000000u);  // monotone map
      best = max(best, (((u64)mu << 32) | (u32)(255 - (lane + 64 * k))));
    }
    for (int off = 1; off < 64; off <<= 1) {
      u64 o = __shfl_xor(best, off);
      best = max(best, o);
    }
    int i  = 255 - (int)(best & 0xFFu);
    u32 mu = (u32)(best >> 32);
    u32 ub = (mu & 0x80000000u) ? (mu & 0x7FFFFFFFu) : ~mu;
    float val = __uint_as_float(ub);
    bool keep = val > 0.0f;
    float4 bi = bxs[wid][i];                 // broadcast read
    float ia  = (bi.z - bi.x) * (bi.w - bi.y);
    if (lane == 0) {
      size_t fo = (size_t)b * NFLAT + (size_t)c * MAXDET + d;
      flat_s[fo] = keep ? val : 0.0f;
      float4 ob;
      if (keep) ob = bi; else { ob.x = ob.y = ob.z = ob.w = 0.0f; }
      ((float4*)flat_b)[fo] = ob;
    }
    for (int k = 0; k < 4; k++) {
      float ty = fmaxf(bi.x, bx[k].x), tx = fmaxf(bi.y, bx[k].y);
      float by = fminf(bi.z, bx[k].z), bxx = fminf(bi.w, bx[k].w);
      float wy = fmaxf(by - ty, 0.0f), wx = fmaxf(bxx - tx, 0.0f);
      float inter = wy * wx;
      float un = ia + ar[k] - inter;
      float iou = inter / fmaxf(un, 1e-8f);
      if (iou >= IOU_T) s[k] = -1.0f;
    }
  }
}

// ---------------- final per-batch top-100 (LDS-staged) ----------------
__global__ void __launch_bounds__(256) k_final(const float* __restrict__ flat_s,
    const float* __restrict__ flat_b, float* __restrict__ out) {
  __shared__ float sdata[NFLAT];   // 36 KB
  __shared__ u32 hist[2048];
  __shared__ u32 suf[256];
  __shared__ int sh2[2];
  __shared__ u64 sel[128];
  __shared__ u32 tie[256];
  __shared__ int cgt, ctie;
  int b = blockIdx.x, tid = threadIdx.x;
  const float2* d2 = (const float2*)(flat_s + (size_t)b * NFLAT);
  for (int i = tid; i < NFLAT / 2; i += 256) {
    float2 v = d2[i];
    sdata[2 * i] = v.x; sdata[2 * i + 1] = v.y;
  }
  __syncthreads();
  auto getv = [&](int i) -> float { return sdata[i]; };
  u32 V; int GT, r;
  radix_select(getv, NFLAT, MAXDET, hist, suf, sh2, tid, V, GT, r);
  if (tid == 0) { cgt = 0; ctie = 0; }
  __syncthreads();
  for (int i = tid; i < NFLAT; i += 256) {
    u32 u = __float_as_uint(sdata[i]);
    if (u > V) {
      int p = atomicAdd(&cgt, 1);
      sel[p] = ((u64)u << 32) | (u32)(~(u32)i);
    } else if (u == V) {
      int p = atomicAdd(&ctie, 1);
      if (p < 256) tie[p] = (u32)i;
    }
  }
  __syncthreads();
  int nt = ctie < 256 ? ctie : 256;
  for (int i = tid + nt; i < 256; i += 256) tie[i] = 0xFFFFFFFFu;
  __syncthreads();
  bitonic_u32_asc(tie, 256, tid);
  for (int i = tid; i < r; i += 256)
    sel[GT + i] = ((u64)V << 32) | (u32)(~tie[i]);
  for (int i = MAXDET + tid; i < 128; i += 256) sel[i] = 0;
  __syncthreads();
  bitonic_u64_asc(sel, 128, tid);
  for (int d = tid; d < MAXDET; d += 256) {
    u64 kk = sel[127 - d];
    u32 u  = (u32)(kk >> 32);
    int fi = (int)(~(u32)kk);
    float4 bb = ((const float4*)flat_b)[(size_t)b * NFLAT + fi];
    float* o = out + ((size_t)b * MAXDET + d) * 6;
    o[0] = bb.x; o[1] = bb.y; o[2] = bb.z; o[3] = bb.w;
    o[4] = (float)(fi / 100 + 1);
    o[5] = __uint_as_float(u);
  }
}

// ---------------- launch ----------------
extern "C" void kernel_launch(void* const* d_in, const int* in_sizes, int n_in,
                              void* d_out, int out_size, void* d_ws, size_t ws_size,
                              hipStream_t stream) {
  const float* enc    = (const float*)d_in[0];
  const float* logits = (const float*)d_in[1];
  const float* anch   = (const float*)d_in[2];
  float* out = (float*)d_out;
  char* ws = (char*)d_ws;

  size_t off = 0;
  auto alloc = [&](size_t bytes) {
    size_t o = off;
    off += (bytes + 255) & ~(size_t)255;
    return o;
  };
  size_t o_dec  = alloc((size_t)BB * AA * 16);        // decoded boxes (float4)
  size_t o_tks  = alloc((size_t)NROWS * KSEL * 4);
  size_t o_tki  = alloc((size_t)NROWS * KSEL * 4);
  size_t o_fls  = alloc((size_t)BB * NFLAT * 4);
  size_t o_flb  = alloc((size_t)BB * NFLAT * 16);
  size_t need_base = off;
  size_t o_sc = off;                                   // chunked sc goes here
  size_t per_batch_sc = ((size_t)NCLS * AA * 4 + 255) & ~(size_t)255; // 6.92 MB

  int CB = 0;
  for (int cb = BB; cb >= 1; cb >>= 1) {
    if (ws_size >= need_base + (size_t)cb * per_batch_sc) { CB = cb; break; }
  }

  float* dec = (float*)(ws + o_dec);
  float* tks = (float*)(ws + o_tks);
  int*   tki = (int*)  (ws + o_tki);
  float* fls = (float*)(ws + o_fls);
  float* flb = (float*)(ws + o_flb);
  float* scp = (float*)(ws + o_sc);

  hipLaunchKernelGGL(k_decode, dim3((BB * AA + 255) / 256), dim3(256), 0, stream,
                     enc, anch, dec);
  if (CB > 0) {
    for (int b0 = 0; b0 < BB; b0 += CB) {
      hipLaunchKernelGGL(k_sigT, dim3((AA + ATILE - 1) / ATILE, CB), dim3(256), 0,
                         stream, logits, scp, b0);
      hipLaunchKernelGGL(k_row, dim3(NCLS * CB), dim3(512), 0, stream,
                         scp, tks, tki, b0 * NCLS);
    }
  } else {
    hipLaunchKernelGGL(k_topk_direct, dim3(NROWS), dim3(256), 0, stream,
                       logits, tks, tki);
  }
  hipLaunchKernelGGL(k_nms, dim3(NROWS / 4), dim3(256), 0, stream,
                     dec, tks, tki, fls, flb);
  hipLaunchKernelGGL(k_final, dim3(BB), dim3(256), 0, stream,
                     fls, flb, out);
}

// Round 5
// 144.247 us; speedup vs baseline: 2.6266x; 1.1211x over previous
//
#include <hip/hip_runtime.h>
#include <stdint.h>
#include <math.h>

typedef unsigned int u32;
typedef unsigned long long u64;

#define BB 8
#define AA 19206
#define CCH 91
#define NCLS 90
#define KSEL 256
#define MAXDET 100
#define NROWS (BB*NCLS)      // 720
#define NFLAT (NCLS*MAXDET)  // 9000
#define IOU_T 0.6f

// ---------------- sigmoid + transpose (per batch-chunk) ----------------
#define ATILE 64
__global__ void __launch_bounds__(256) k_sigT(const float* __restrict__ logits,
                                              float* __restrict__ sc, int b0) {
  __shared__ __align__(16) float tile[ATILE * CCH];  // 23.3 KB
  int bl = blockIdx.y;            // local batch within chunk
  int b  = b0 + bl;               // global batch
  int a0 = blockIdx.x * ATILE;
  int nt = AA - a0; if (nt > ATILE) nt = ATILE;
  int nload = nt * CCH;           // even
  const float* src = logits + ((size_t)b * AA + a0) * CCH;   // 8B aligned
  const float2* s2 = (const float2*)src;
  int n2 = nload >> 1;
  for (int i = threadIdx.x; i < n2; i += 256) ((float2*)tile)[i] = s2[i];
  __syncthreads();
  for (int j = threadIdx.x; j < ATILE * NCLS; j += 256) {
    int c  = j >> 6;       // whole wave shares c -> coalesced store
    int ai = j & 63;
    if (ai < nt) {
      float x = tile[ai * CCH + (c + 1)];
      float s = 1.0f / (1.0f + expf(-x));
      sc[((size_t)bl * NCLS + c) * AA + a0 + ai] = s;
    }
  }
}

// ---------------- per-row top-256: 2 global passes (L3-hot), small LDS ------
__global__ void __launch_bounds__(512) k_row(const float* __restrict__ sc,
    float* __restrict__ tks, int* __restrict__ tki, int row0) {
  __shared__ u32 hist[256];
  __shared__ u32 suf[256];
  __shared__ u64 cand[512];
  __shared__ int shBs, ctr;
  int rl  = blockIdx.x;
  int row = row0 + rl;
  int tid = threadIdx.x;
  const float2* src = (const float2*)(sc + (size_t)rl * AA);  // AA even
  if (tid < 256) hist[tid] = 0;
  if (tid == 0) ctr = 0;
  __syncthreads();
  for (int i = tid; i < AA / 2; i += 512) {
    float2 v = src[i];
    atomicAdd(&hist[min(255, (int)(v.x * 256.0f))], 1u);  // monotone bin
    atomicAdd(&hist[min(255, (int)(v.y * 256.0f))], 1u);
  }
  __syncthreads();
  if (tid < 256) suf[tid] = hist[tid];
  __syncthreads();
  for (int off = 1; off < 256; off <<= 1) {
    u32 v = 0;
    if (tid < 256 && tid + off < 256) v = suf[tid + off];
    __syncthreads();
    if (tid < 256) suf[tid] += v;
    __syncthreads();
  }
  if (tid < 256) {
    u32 nxt = (tid < 255) ? suf[tid + 1] : 0u;
    if (suf[tid] >= (u32)KSEL && nxt < (u32)KSEL) shBs = tid;
  }
  __syncthreads();
  int Bs = shBs;
  int lane = tid & 63;
  // pass 2: L2/L3-hot re-read, wave-aggregated LDS append of bins >= Bs
  for (int i = tid; i < AA / 2; i += 512) {
    float2 v = src[i];
    {
      bool p = min(255, (int)(v.x * 256.0f)) >= Bs;
      u64 m = __ballot(p);
      if (p) {
        int leader = (int)(__ffsll((long long)m) - 1);
        int base = 0;
        if (lane == leader) base = atomicAdd(&ctr, (int)__popcll(m));
        base = __shfl(base, leader);
        int pos = base + (int)__popcll(m & ((1ull << lane) - 1ull));
        if (pos < 512)
          cand[pos] = ((u64)__float_as_uint(v.x) << 32) | (u32)(~(u32)(2 * i));
      }
    }
    {
      bool p = min(255, (int)(v.y * 256.0f)) >= Bs;
      u64 m = __ballot(p);
      if (p) {
        int leader = (int)(__ffsll((long long)m) - 1);
        int base = 0;
        if (lane == leader) base = atomicAdd(&ctr, (int)__popcll(m));
        base = __shfl(base, leader);
        int pos = base + (int)__popcll(m & ((1ull << lane) - 1ull));
        if (pos < 512)
          cand[pos] = ((u64)__float_as_uint(v.y) << 32) | (u32)(~(u32)(2 * i + 1));
      }
    }
  }
  __syncthreads();
  int n = ctr < 512 ? ctr : 512;
  for (int i = n + tid; i < 512; i += 512) cand[i] = 0;  // pad sorts low
  __syncthreads();
  // bitonic sort 512 ascending, 1 element per thread
  for (int k = 2; k <= 512; k <<= 1) {
    for (int j = k >> 1; j > 0; j >>= 1) {
      int l = tid ^ j;
      if (l > tid) {
        u64 x = cand[tid], y = cand[l];
        bool asc = ((tid & k) == 0);
        if ((x > y) == asc) { cand[tid] = y; cand[l] = x; }
      }
      __syncthreads();
    }
  }
  if (tid < KSEL) {
    u64 kk = cand[511 - tid];
    tks[(size_t)row * KSEL + tid] = __uint_as_float((u32)(kk >> 32));
    tki[(size_t)row * KSEL + tid] = (int)(~(u32)kk);
  }
}

// ---------------- bitonic sorts (block of 256 threads) ----------------
__device__ inline void bitonic_u64_asc(u64* a, int n, int tid) {
  for (int k = 2; k <= n; k <<= 1) {
    for (int j = k >> 1; j > 0; j >>= 1) {
      for (int i = tid; i < n; i += 256) {
        int l = i ^ j;
        if (l > i) {
          u64 x = a[i], y = a[l];
          bool asc = ((i & k) == 0);
          if ((x > y) == asc) { a[i] = y; a[l] = x; }
        }
      }
      __syncthreads();
    }
  }
}
__device__ inline void bitonic_u32_asc(u32* a, int n, int tid) {
  for (int k = 2; k <= n; k <<= 1) {
    for (int j = k >> 1; j > 0; j >>= 1) {
      for (int i = tid; i < n; i += 256) {
        int l = i ^ j;
        if (l > i) {
          u32 x = a[i], y = a[l];
          bool asc = ((i & k) == 0);
          if ((x > y) == asc) { a[i] = y; a[l] = x; }
        }
      }
      __syncthreads();
    }
  }
}

// ---------------- exact radix select (rank kwant, descending) ----------------
template<typename F>
__device__ inline void radix_select(F getv, int n, int kwant,
    u32* hist, u32* suf, int* sh2, int tid,
    u32& V_out, int& GT_out, int& r_out) {
  int r = kwant; u32 V = 0; int GT = 0;
  for (int lvl = 0; lvl < 3; lvl++) {
    int shift = (lvl == 0) ? 19 : ((lvl == 1) ? 8 : 0);
    int nbins = (lvl == 2) ? 256 : 2048;
    for (int i = tid; i < nbins; i += 256) hist[i] = 0;
    __syncthreads();
    for (int idx = tid; idx < n; idx += 256) {
      u32 u = __float_as_uint(getv(idx));
      bool ok = (lvl == 0) || (lvl == 1 ? ((u >> 19) == (V >> 19))
                                        : ((u >> 8)  == (V >> 8)));
      u64 zm = __ballot(ok && u == 0u);
      if (ok) {
        if (u == 0u) {
          if ((int)(threadIdx.x & 63) == (int)(__ffsll((long long)zm) - 1))
            atomicAdd(&hist[0], (u32)__popcll(zm));
        } else {
          atomicAdd(&hist[(u >> shift) & (u32)(nbins - 1)], 1u);
        }
      }
    }
    __syncthreads();
    int G = nbins >> 8;
    u32 ps = 0;
    for (int g = 0; g < G; g++) ps += hist[tid * G + g];
    suf[tid] = ps;
    __syncthreads();
    for (int off = 1; off < 256; off <<= 1) {
      u32 v = (tid + off < 256) ? suf[tid + off] : 0u;
      __syncthreads();
      suf[tid] += v;
      __syncthreads();
    }
    u32 sufnext = (tid < 255) ? suf[tid + 1] : 0u;
    if (suf[tid] >= (u32)r && sufnext < (u32)r) {
      u32 cum = sufnext; int kb = tid * G;
      for (int bin = tid * G + G - 1; bin >= tid * G; bin--) {
        cum += hist[bin];
        if (cum >= (u32)r) { kb = bin; break; }
      }
      sh2[0] = kb;
      sh2[1] = (int)(cum - hist[kb]);
    }
    __syncthreads();
    int kb = sh2[0], gt = sh2[1];
    r -= gt; GT += gt; V |= ((u32)kb) << shift;
    __syncthreads();
  }
  V_out = V; GT_out = GT; r_out = r;
}

// ---------------- fallback: direct strided top-256 (small ws only) ----------
__global__ void __launch_bounds__(256) k_topk_direct(const float* __restrict__ src,
    float* __restrict__ tks, int* __restrict__ tki) {
  __shared__ u32 hist[2048];
  __shared__ u32 suf[256];
  __shared__ int sh2[2];
  __shared__ u64 sel[KSEL];
  __shared__ u32 tie[512];
  __shared__ int cgt, ctie;
  int row = blockIdx.x, tid = threadIdx.x;
  int b = row / NCLS, c = row % NCLS;
  const float* base = src + (size_t)b * AA * CCH + (c + 1);
  auto getv = [&](int i) -> float {
    float x = base[(size_t)i * CCH]; return 1.0f / (1.0f + expf(-x));
  };
  u32 V; int GT, r;
  radix_select(getv, AA, KSEL, hist, suf, sh2, tid, V, GT, r);
  if (tid == 0) { cgt = 0; ctie = 0; }
  __syncthreads();
  for (int i = tid; i < AA; i += 256) {
    u32 u = __float_as_uint(getv(i));
    if (u > V) {
      int p = atomicAdd(&cgt, 1);
      sel[p] = ((u64)u << 32) | (u32)(~(u32)i);
    } else if (u == V) {
      int p = atomicAdd(&ctie, 1);
      if (p < 512) tie[p] = (u32)i;
    }
  }
  __syncthreads();
  int nt = ctie < 512 ? ctie : 512;
  for (int i = tid + nt; i < 512; i += 256) tie[i] = 0xFFFFFFFFu;
  __syncthreads();
  bitonic_u32_asc(tie, 512, tid);
  for (int i = tid; i < r; i += 256)
    sel[GT + i] = ((u64)V << 32) | (u32)(~tie[i]);
  __syncthreads();
  bitonic_u64_asc(sel, KSEL, tid);
  for (int j = tid; j < KSEL; j += 256) {
    u64 kk = sel[KSEL - 1 - j];
    tks[(size_t)row * KSEL + j] = __uint_as_float((u32)(kk >> 32));
    tki[(size_t)row * KSEL + j] = (int)(~(u32)kk);
  }
}

// ---------------- DPP helpers ----------------
template<int CTRL>
__device__ inline float dpp_max(float x) {
  float y = __int_as_float(__builtin_amdgcn_update_dpp(
      __float_as_int(x), __float_as_int(x), CTRL, 0xf, 0xf, false));
  return fmaxf(x, y);
}
__device__ inline float rdlane(float x, int l) {
  return __int_as_float(__builtin_amdgcn_readlane(__float_as_int(x), l));
}

__device__ inline float4 decode1(const float* __restrict__ enc,
                                 const float* __restrict__ anch, int b, int ai) {
  float4 e  = ((const float4*)enc)[(size_t)b * AA + ai];
  float4 an = ((const float4*)anch)[ai];
  float ty = e.x / 10.0f, tx = e.y / 10.0f, th = e.z / 5.0f, tw = e.w / 5.0f;
  float yc = ty * an.z + an.x;
  float xc = tx * an.w + an.y;
  float h  = expf(th) * an.z;
  float w  = expf(tw) * an.w;
  float4 o;
  o.x = yc - h * 0.5f; o.y = xc - w * 0.5f; o.z = yc + h * 0.5f; o.w = xc + w * 0.5f;
  return o;
}

// ---------------- NMS: one wave per (b,c) row, DPP argmax, no LDS ----------
// List position j = lane*4 + k (lexicographic (lane,k)) so f32-max + lowest-
// lane ballot + lowest-k scan reproduces argmax's first-occurrence exactly.
__global__ void __launch_bounds__(256) k_nms(const float* __restrict__ enc,
    const float* __restrict__ anch,
    const float* __restrict__ tks, const int* __restrict__ tki,
    float* __restrict__ flat_s, float* __restrict__ flat_b) {
  int wid = threadIdx.x >> 6, lane = threadIdx.x & 63;
  int row = blockIdx.x * 4 + wid;
  int b = row / NCLS, c = row % NCLS;
  float4 sv = ((const float4*)(tks + (size_t)row * KSEL))[lane];
  int4   iv = ((const int4*)(tki + (size_t)row * KSEL))[lane];
  float s0 = sv.x, s1 = sv.y, s2 = sv.z, s3 = sv.w;
  float4 b0 = decode1(enc, anch, b, iv.x);
  float4 b1 = decode1(enc, anch, b, iv.y);
  float4 b2 = decode1(enc, anch, b, iv.z);
  float4 b3 = decode1(enc, anch, b, iv.w);
  float a0 = (b0.z - b0.x) * (b0.w - b0.y);
  float a1 = (b1.z - b1.x) * (b1.w - b1.y);
  float a2 = (b2.z - b2.x) * (b2.w - b2.y);
  float a3 = (b3.z - b3.x) * (b3.w - b3.y);
  size_t fo = (size_t)b * NFLAT + (size_t)c * MAXDET;
  int d = 0;
  for (; d < MAXDET; ++d) {
    // per-lane argmax over k (strict > keeps lowest k)
    float m = s0; int mk = 0;
    if (s1 > m) { m = s1; mk = 1; }
    if (s2 > m) { m = s2; mk = 2; }
    if (s3 > m) { m = s3; mk = 3; }
    float bcx = b0.x, bcy = b0.y, bcz = b0.z, bcw = b0.w;
    if (mk == 1) { bcx = b1.x; bcy = b1.y; bcz = b1.z; bcw = b1.w; }
    if (mk == 2) { bcx = b2.x; bcy = b2.y; bcz = b2.z; bcw = b2.w; }
    if (mk == 3) { bcx = b3.x; bcy = b3.y; bcz = b3.z; bcw = b3.w; }
    // wave max via DPP (VALU latency, no LDS)
    float x = m;
    x = dpp_max<0x111>(x);   // row_shr:1
    x = dpp_max<0x112>(x);   // row_shr:2
    x = dpp_max<0x114>(x);   // row_shr:4
    x = dpp_max<0x118>(x);   // row_shr:8
    x = dpp_max<0x142>(x);   // row_bcast:15
    x = dpp_max<0x143>(x);   // row_bcast:31
    float wmax = rdlane(x, 63);
    if (!(wmax > 0.0f)) break;          // uniform: rest are zeros
    u64 mask = __ballot(m == wmax);
    int wlane = (int)__builtin_ctzll(mask);   // lowest lane = lowest j
    float bix = rdlane(bcx, wlane);
    float biy = rdlane(bcy, wlane);
    float biz = rdlane(bcz, wlane);
    float biw = rdlane(bcw, wlane);
    if (lane == 0) {
      flat_s[fo + d] = wmax;
      float4 ob; ob.x = bix; ob.y = biy; ob.z = biz; ob.w = biw;
      ((float4*)flat_b)[fo + d] = ob;
    }
    float ia = (biz - bix) * (biw - biy);
#define SUPP(BX, SK, AK) { \
      float ty = fmaxf(bix, BX.x), tx = fmaxf(biy, BX.y); \
      float by = fminf(biz, BX.z), bw = fminf(biw, BX.w); \
      float wy = fmaxf(by - ty, 0.0f), wx = fmaxf(bw - tx, 0.0f); \
      float inter = wy * wx; \
      float un = ia + AK - inter; \
      float iou = inter / fmaxf(un, 1e-8f); \
      if (iou >= IOU_T) SK = -1.0f; }
    SUPP(b0, s0, a0)
    SUPP(b1, s1, a1)
    SUPP(b2, s2, a2)
    SUPP(b3, s3, a3)
#undef SUPP
  }
  // zero-fill remaining detections
  for (int dd = d + lane; dd < MAXDET; dd += 64) {
    flat_s[fo + dd] = 0.0f;
    float4 z; z.x = z.y = z.z = z.w = 0.0f;
    ((float4*)flat_b)[fo + dd] = z;
  }
}

// ---------------- final per-batch top-100 (LDS-staged) ----------------
__global__ void __launch_bounds__(256) k_final(const float* __restrict__ flat_s,
    const float* __restrict__ flat_b, float* __restrict__ out) {
  __shared__ float sdata[NFLAT];   // 36 KB
  __shared__ u32 hist[2048];
  __shared__ u32 suf[256];
  __shared__ int sh2[2];
  __shared__ u64 sel[128];
  __shared__ u32 tie[256];
  __shared__ int cgt, ctie;
  int b = blockIdx.x, tid = threadIdx.x;
  const float2* d2 = (const float2*)(flat_s + (size_t)b * NFLAT);
  for (int i = tid; i < NFLAT / 2; i += 256) {
    float2 v = d2[i];
    sdata[2 * i] = v.x; sdata[2 * i + 1] = v.y;
  }
  __syncthreads();
  auto getv = [&](int i) -> float { return sdata[i]; };
  u32 V; int GT, r;
  radix_select(getv, NFLAT, MAXDET, hist, suf, sh2, tid, V, GT, r);
  if (tid == 0) { cgt = 0; ctie = 0; }
  __syncthreads();
  for (int i = tid; i < NFLAT; i += 256) {
    u32 u = __float_as_uint(sdata[i]);
    if (u > V) {
      int p = atomicAdd(&cgt, 1);
      sel[p] = ((u64)u << 32) | (u32)(~(u32)i);
    } else if (u == V) {
      int p = atomicAdd(&ctie, 1);
      if (p < 256) tie[p] = (u32)i;
    }
  }
  __syncthreads();
  int nt = ctie < 256 ? ctie : 256;
  for (int i = tid + nt; i < 256; i += 256) tie[i] = 0xFFFFFFFFu;
  __syncthreads();
  bitonic_u32_asc(tie, 256, tid);
  for (int i = tid; i < r; i += 256)
    sel[GT + i] = ((u64)V << 32) | (u32)(~tie[i]);
  for (int i = MAXDET + tid; i < 128; i += 256) sel[i] = 0;
  __syncthreads();
  bitonic_u64_asc(sel, 128, tid);
  for (int d = tid; d < MAXDET; d += 256) {
    u64 kk = sel[127 - d];
    u32 u  = (u32)(kk >> 32);
    int fi = (int)(~(u32)kk);
    float4 bb = ((const float4*)flat_b)[(size_t)b * NFLAT + fi];
    float* o = out + ((size_t)b * MAXDET + d) * 6;
    o[0] = bb.x; o[1] = bb.y; o[2] = bb.z; o[3] = bb.w;
    o[4] = (float)(fi / 100 + 1);
    o[5] = __uint_as_float(u);
  }
}

// ---------------- launch ----------------
extern "C" void kernel_launch(void* const* d_in, const int* in_sizes, int n_in,
                              void* d_out, int out_size, void* d_ws, size_t ws_size,
                              hipStream_t stream) {
  const float* enc    = (const float*)d_in[0];
  const float* logits = (const float*)d_in[1];
  const float* anch   = (const float*)d_in[2];
  float* out = (float*)d_out;
  char* ws = (char*)d_ws;

  size_t off = 0;
  auto alloc = [&](size_t bytes) {
    size_t o = off;
    off += (bytes + 255) & ~(size_t)255;
    return o;
  };
  size_t o_tks  = alloc((size_t)NROWS * KSEL * 4);
  size_t o_tki  = alloc((size_t)NROWS * KSEL * 4);
  size_t o_fls  = alloc((size_t)BB * NFLAT * 4);
  size_t o_flb  = alloc((size_t)BB * NFLAT * 16);
  size_t need_base = off;
  size_t o_sc = off;                                   // chunked sc goes here
  size_t per_batch_sc = ((size_t)NCLS * AA * 4 + 255) & ~(size_t)255; // 6.92 MB

  int CB = 0;
  for (int cb = BB; cb >= 1; cb >>= 1) {
    if (ws_size >= need_base + (size_t)cb * per_batch_sc) { CB = cb; break; }
  }

  float* tks = (float*)(ws + o_tks);
  int*   tki = (int*)  (ws + o_tki);
  float* fls = (float*)(ws + o_fls);
  float* flb = (float*)(ws + o_flb);
  float* scp = (float*)(ws + o_sc);

  if (CB > 0) {
    for (int b0 = 0; b0 < BB; b0 += CB) {
      hipLaunchKernelGGL(k_sigT, dim3((AA + ATILE - 1) / ATILE, CB), dim3(256), 0,
                         stream, logits, scp, b0);
      hipLaunchKernelGGL(k_row, dim3(NCLS * CB), dim3(512), 0, stream,
                         scp, tks, tki, b0 * NCLS);
    }
  } else {
    hipLaunchKernelGGL(k_topk_direct, dim3(NROWS), dim3(256), 0, stream,
                       logits, tks, tki);
  }
  hipLaunchKernelGGL(k_nms, dim3(NROWS / 4), dim3(256), 0, stream,
                     enc, anch, tks, tki, fls, flb);
  hipLaunchKernelGGL(k_final, dim3(BB), dim3(256), 0, stream,
                     fls, flb, out);
}

// Round 6
// 142.064 us; speedup vs baseline: 2.6670x; 1.0154x over previous
//
#include <hip/hip_runtime.h>
#include <stdint.h>
#include <math.h>

typedef unsigned int u32;
typedef unsigned long long u64;

#define BB 8
#define AA 19206
#define CCH 91
#define NCLS 90
#define KSEL 256
#define MAXDET 100
#define NROWS (BB*NCLS)      // 720
#define NFLAT (NCLS*MAXDET)  // 9000
#define IOU_T 0.6f

// ---------------- sigmoid + transpose (per batch-chunk) ----------------
#define ATILE 64
__global__ void __launch_bounds__(256) k_sigT(const float* __restrict__ logits,
                                              float* __restrict__ sc, int b0) {
  __shared__ __align__(16) float tile[ATILE * CCH];  // 23.3 KB
  int bl = blockIdx.y;            // local batch within chunk
  int b  = b0 + bl;               // global batch
  int a0 = blockIdx.x * ATILE;
  int nt = AA - a0; if (nt > ATILE) nt = ATILE;
  int nload = nt * CCH;           // even
  const float* src = logits + ((size_t)b * AA + a0) * CCH;   // 8B aligned
  const float2* s2 = (const float2*)src;
  int n2 = nload >> 1;
  for (int i = threadIdx.x; i < n2; i += 256) ((float2*)tile)[i] = s2[i];
  __syncthreads();
  for (int j = threadIdx.x; j < ATILE * NCLS; j += 256) {
    int c  = j >> 6;       // whole wave shares c -> coalesced store
    int ai = j & 63;
    if (ai < nt) {
      float x = tile[ai * CCH + (c + 1)];
      float s = 1.0f / (1.0f + expf(-x));
      sc[((size_t)bl * NCLS + c) * AA + a0 + ai] = s;
    }
  }
}

// ---------------- per-row top-256: 2 global passes (L3-hot), small LDS ------
__global__ void __launch_bounds__(512) k_row(const float* __restrict__ sc,
    float* __restrict__ tks, int* __restrict__ tki, int row0) {
  __shared__ u32 hist[256];
  __shared__ u32 suf[256];
  __shared__ u64 cand[512];
  __shared__ int shBs, ctr;
  int rl  = blockIdx.x;
  int row = row0 + rl;
  int tid = threadIdx.x;
  const float2* src = (const float2*)(sc + (size_t)rl * AA);  // AA even
  if (tid < 256) hist[tid] = 0;
  if (tid == 0) ctr = 0;
  __syncthreads();
  for (int i = tid; i < AA / 2; i += 512) {
    float2 v = src[i];
    atomicAdd(&hist[min(255, (int)(v.x * 256.0f))], 1u);  // monotone bin
    atomicAdd(&hist[min(255, (int)(v.y * 256.0f))], 1u);
  }
  __syncthreads();
  if (tid < 256) suf[tid] = hist[tid];
  __syncthreads();
  for (int off = 1; off < 256; off <<= 1) {
    u32 v = 0;
    if (tid < 256 && tid + off < 256) v = suf[tid + off];
    __syncthreads();
    if (tid < 256) suf[tid] += v;
    __syncthreads();
  }
  if (tid < 256) {
    u32 nxt = (tid < 255) ? suf[tid + 1] : 0u;
    if (suf[tid] >= (u32)KSEL && nxt < (u32)KSEL) shBs = tid;
  }
  __syncthreads();
  int Bs = shBs;
  int lane = tid & 63;
  // pass 2: L2/L3-hot re-read, wave-aggregated LDS append of bins >= Bs
  for (int i = tid; i < AA / 2; i += 512) {
    float2 v = src[i];
    {
      bool p = min(255, (int)(v.x * 256.0f)) >= Bs;
      u64 m = __ballot(p);
      if (p) {
        int leader = (int)(__ffsll((long long)m) - 1);
        int base = 0;
        if (lane == leader) base = atomicAdd(&ctr, (int)__popcll(m));
        base = __shfl(base, leader);
        int pos = base + (int)__popcll(m & ((1ull << lane) - 1ull));
        if (pos < 512)
          cand[pos] = ((u64)__float_as_uint(v.x) << 32) | (u32)(~(u32)(2 * i));
      }
    }
    {
      bool p = min(255, (int)(v.y * 256.0f)) >= Bs;
      u64 m = __ballot(p);
      if (p) {
        int leader = (int)(__ffsll((long long)m) - 1);
        int base = 0;
        if (lane == leader) base = atomicAdd(&ctr, (int)__popcll(m));
        base = __shfl(base, leader);
        int pos = base + (int)__popcll(m & ((1ull << lane) - 1ull));
        if (pos < 512)
          cand[pos] = ((u64)__float_as_uint(v.y) << 32) | (u32)(~(u32)(2 * i + 1));
      }
    }
  }
  __syncthreads();
  int n = ctr < 512 ? ctr : 512;
  for (int i = n + tid; i < 512; i += 512) cand[i] = 0;  // pad sorts low
  __syncthreads();
  // bitonic sort 512 ascending, 1 element per thread
  for (int k = 2; k <= 512; k <<= 1) {
    for (int j = k >> 1; j > 0; j >>= 1) {
      int l = tid ^ j;
      if (l > tid) {
        u64 x = cand[tid], y = cand[l];
        bool asc = ((tid & k) == 0);
        if ((x > y) == asc) { cand[tid] = y; cand[l] = x; }
      }
      __syncthreads();
    }
  }
  if (tid < KSEL) {
    u64 kk = cand[511 - tid];
    tks[(size_t)row * KSEL + tid] = __uint_as_float((u32)(kk >> 32));
    tki[(size_t)row * KSEL + tid] = (int)(~(u32)kk);
  }
}

// ---------------- bitonic sorts (block of 256 threads) ----------------
__device__ inline void bitonic_u64_asc(u64* a, int n, int tid) {
  for (int k = 2; k <= n; k <<= 1) {
    for (int j = k >> 1; j > 0; j >>= 1) {
      for (int i = tid; i < n; i += 256) {
        int l = i ^ j;
        if (l > i) {
          u64 x = a[i], y = a[l];
          bool asc = ((i & k) == 0);
          if ((x > y) == asc) { a[i] = y; a[l] = x; }
        }
      }
      __syncthreads();
    }
  }
}
__device__ inline void bitonic_u32_asc(u32* a, int n, int tid) {
  for (int k = 2; k <= n; k <<= 1) {
    for (int j = k >> 1; j > 0; j >>= 1) {
      for (int i = tid; i < n; i += 256) {
        int l = i ^ j;
        if (l > i) {
          u32 x = a[i], y = a[l];
          bool asc = ((i & k) == 0);
          if ((x > y) == asc) { a[i] = y; a[l] = x; }
        }
      }
      __syncthreads();
    }
  }
}

// ---------------- exact radix select (rank kwant, descending) ----------------
template<typename F>
__device__ inline void radix_select(F getv, int n, int kwant,
    u32* hist, u32* suf, int* sh2, int tid,
    u32& V_out, int& GT_out, int& r_out) {
  int r = kwant; u32 V = 0; int GT = 0;
  for (int lvl = 0; lvl < 3; lvl++) {
    int shift = (lvl == 0) ? 19 : ((lvl == 1) ? 8 : 0);
    int nbins = (lvl == 2) ? 256 : 2048;
    for (int i = tid; i < nbins; i += 256) hist[i] = 0;
    __syncthreads();
    for (int idx = tid; idx < n; idx += 256) {
      u32 u = __float_as_uint(getv(idx));
      bool ok = (lvl == 0) || (lvl == 1 ? ((u >> 19) == (V >> 19))
                                        : ((u >> 8)  == (V >> 8)));
      u64 zm = __ballot(ok && u == 0u);
      if (ok) {
        if (u == 0u) {
          if ((int)(threadIdx.x & 63) == (int)(__ffsll((long long)zm) - 1))
            atomicAdd(&hist[0], (u32)__popcll(zm));
        } else {
          atomicAdd(&hist[(u >> shift) & (u32)(nbins - 1)], 1u);
        }
      }
    }
    __syncthreads();
    int G = nbins >> 8;
    u32 ps = 0;
    for (int g = 0; g < G; g++) ps += hist[tid * G + g];
    suf[tid] = ps;
    __syncthreads();
    for (int off = 1; off < 256; off <<= 1) {
      u32 v = (tid + off < 256) ? suf[tid + off] : 0u;
      __syncthreads();
      suf[tid] += v;
      __syncthreads();
    }
    u32 sufnext = (tid < 255) ? suf[tid + 1] : 0u;
    if (suf[tid] >= (u32)r && sufnext < (u32)r) {
      u32 cum = sufnext; int kb = tid * G;
      for (int bin = tid * G + G - 1; bin >= tid * G; bin--) {
        cum += hist[bin];
        if (cum >= (u32)r) { kb = bin; break; }
      }
      sh2[0] = kb;
      sh2[1] = (int)(cum - hist[kb]);
    }
    __syncthreads();
    int kb = sh2[0], gt = sh2[1];
    r -= gt; GT += gt; V |= ((u32)kb) << shift;
    __syncthreads();
  }
  V_out = V; GT_out = GT; r_out = r;
}

// ---------------- fallback: direct strided top-256 (small ws only) ----------
__global__ void __launch_bounds__(256) k_topk_direct(const float* __restrict__ src,
    float* __restrict__ tks, int* __restrict__ tki) {
  __shared__ u32 hist[2048];
  __shared__ u32 suf[256];
  __shared__ int sh2[2];
  __shared__ u64 sel[KSEL];
  __shared__ u32 tie[512];
  __shared__ int cgt, ctie;
  int row = blockIdx.x, tid = threadIdx.x;
  int b = row / NCLS, c = row % NCLS;
  const float* base = src + (size_t)b * AA * CCH + (c + 1);
  auto getv = [&](int i) -> float {
    float x = base[(size_t)i * CCH]; return 1.0f / (1.0f + expf(-x));
  };
  u32 V; int GT, r;
  radix_select(getv, AA, KSEL, hist, suf, sh2, tid, V, GT, r);
  if (tid == 0) { cgt = 0; ctie = 0; }
  __syncthreads();
  for (int i = tid; i < AA; i += 256) {
    u32 u = __float_as_uint(getv(i));
    if (u > V) {
      int p = atomicAdd(&cgt, 1);
      sel[p] = ((u64)u << 32) | (u32)(~(u32)i);
    } else if (u == V) {
      int p = atomicAdd(&ctie, 1);
      if (p < 512) tie[p] = (u32)i;
    }
  }
  __syncthreads();
  int nt = ctie < 512 ? ctie : 512;
  for (int i = tid + nt; i < 512; i += 256) tie[i] = 0xFFFFFFFFu;
  __syncthreads();
  bitonic_u32_asc(tie, 512, tid);
  for (int i = tid; i < r; i += 256)
    sel[GT + i] = ((u64)V << 32) | (u32)(~tie[i]);
  __syncthreads();
  bitonic_u64_asc(sel, KSEL, tid);
  for (int j = tid; j < KSEL; j += 256) {
    u64 kk = sel[KSEL - 1 - j];
    tks[(size_t)row * KSEL + j] = __uint_as_float((u32)(kk >> 32));
    tki[(size_t)row * KSEL + j] = (int)(~(u32)kk);
  }
}

// ---------------- helpers ----------------
__device__ inline float rdlane(float x, int l) {
  return __int_as_float(__builtin_amdgcn_readlane(__float_as_int(x), l));
}

__device__ inline float4 decode1(const float* __restrict__ enc,
                                 const float* __restrict__ anch, int b, int ai) {
  float4 e  = ((const float4*)enc)[(size_t)b * AA + ai];
  float4 an = ((const float4*)anch)[ai];
  float ty = e.x / 10.0f, tx = e.y / 10.0f, th = e.z / 5.0f, tw = e.w / 5.0f;
  float yc = ty * an.z + an.x;
  float xc = tx * an.w + an.y;
  float h  = expf(th) * an.z;
  float w  = expf(tw) * an.w;
  float4 o;
  o.x = yc - h * 0.5f; o.y = xc - w * 0.5f; o.z = yc + h * 0.5f; o.w = xc + w * 0.5f;
  return o;
}

// ---------------- NMS v2: sorted-scan with 256-bit alive mask --------------
// tks is sorted (value desc, index asc) == argmax first-occurrence order.
// Suppression only removes entries, so repeated-argmax == scan for next
// alive entry. Position p = k*64 + lane; alive mask = 4 x 64-bit words.
__global__ void __launch_bounds__(256) k_nms(const float* __restrict__ enc,
    const float* __restrict__ anch,
    const float* __restrict__ tks, const int* __restrict__ tki,
    float* __restrict__ flat_s, float* __restrict__ flat_b) {
  int wid = threadIdx.x >> 6, lane = threadIdx.x & 63;
  int row = blockIdx.x * 4 + wid;
  int b = row / NCLS, c = row % NCLS;
  const float* trow = tks + (size_t)row * KSEL;
  const int*   irow = tki + (size_t)row * KSEL;
  float s0 = trow[lane], s1 = trow[64 + lane], s2 = trow[128 + lane], s3 = trow[192 + lane];
  int   i0 = irow[lane], i1 = irow[64 + lane], i2 = irow[128 + lane], i3 = irow[192 + lane];
  float4 B0 = decode1(enc, anch, b, i0);
  float4 B1 = decode1(enc, anch, b, i1);
  float4 B2 = decode1(enc, anch, b, i2);
  float4 B3 = decode1(enc, anch, b, i3);
  float a0 = (B0.z - B0.x) * (B0.w - B0.y);
  float a1 = (B1.z - B1.x) * (B1.w - B1.y);
  float a2 = (B2.z - B2.x) * (B2.w - B2.y);
  float a3 = (B3.z - B3.x) * (B3.w - B3.y);
  u64 m0 = __ballot(s0 > 0.0f);
  u64 m1 = __ballot(s1 > 0.0f);
  u64 m2 = __ballot(s2 > 0.0f);
  u64 m3 = __ballot(s3 > 0.0f);
  size_t fo = (size_t)b * NFLAT + (size_t)c * MAXDET;
  int d = 0;
  while (d < MAXDET) {
    int kw; u64 w;
    if      (m0) { kw = 0; w = m0; }
    else if (m1) { kw = 1; w = m1; }
    else if (m2) { kw = 2; w = m2; }
    else if (m3) { kw = 3; w = m3; }
    else break;
    int lw = (int)__builtin_ctzll(w);
    float sw, wx_, wy_, wz_, ww_;
    if (kw == 0) {
      sw = rdlane(s0, lw);
      wx_ = rdlane(B0.x, lw); wy_ = rdlane(B0.y, lw);
      wz_ = rdlane(B0.z, lw); ww_ = rdlane(B0.w, lw);
    } else if (kw == 1) {
      sw = rdlane(s1, lw);
      wx_ = rdlane(B1.x, lw); wy_ = rdlane(B1.y, lw);
      wz_ = rdlane(B1.z, lw); ww_ = rdlane(B1.w, lw);
    } else if (kw == 2) {
      sw = rdlane(s2, lw);
      wx_ = rdlane(B2.x, lw); wy_ = rdlane(B2.y, lw);
      wz_ = rdlane(B2.z, lw); ww_ = rdlane(B2.w, lw);
    } else {
      sw = rdlane(s3, lw);
      wx_ = rdlane(B3.x, lw); wy_ = rdlane(B3.y, lw);
      wz_ = rdlane(B3.z, lw); ww_ = rdlane(B3.w, lw);
    }
    if (lane == 0) {
      flat_s[fo + d] = sw;
      float4 ob; ob.x = wx_; ob.y = wy_; ob.z = wz_; ob.w = ww_;
      ((float4*)flat_b)[fo + d] = ob;
    }
    float ia = (wz_ - wx_) * (ww_ - wy_);
#define SUP(BX, AK, MK) { \
      float ty = fmaxf(wx_, BX.x), tx = fmaxf(wy_, BX.y); \
      float by = fminf(wz_, BX.z), bw = fminf(ww_, BX.w); \
      float hh = fmaxf(by - ty, 0.0f), wv = fmaxf(bw - tx, 0.0f); \
      float inter = hh * wv; \
      float un = ia + AK - inter; \
      float iou = inter / fmaxf(un, 1e-8f); \
      u64 cm = __ballot(iou >= IOU_T); \
      MK &= ~cm; }
    SUP(B0, a0, m0)
    SUP(B1, a1, m1)
    SUP(B2, a2, m2)
    SUP(B3, a3, m3)
#undef SUP
    d++;
  }
  // zero-fill remaining detections
  for (int dd = d + lane; dd < MAXDET; dd += 64) {
    flat_s[fo + dd] = 0.0f;
    float4 z; z.x = z.y = z.z = z.w = 0.0f;
    ((float4*)flat_b)[fo + dd] = z;
  }
}

// ---------------- final per-batch top-100 (LDS-staged) ----------------
__global__ void __launch_bounds__(256) k_final(const float* __restrict__ flat_s,
    const float* __restrict__ flat_b, float* __restrict__ out) {
  __shared__ float sdata[NFLAT];   // 36 KB
  __shared__ u32 hist[2048];
  __shared__ u32 suf[256];
  __shared__ int sh2[2];
  __shared__ u64 sel[128];
  __shared__ u32 tie[256];
  __shared__ int cgt, ctie;
  int b = blockIdx.x, tid = threadIdx.x;
  const float2* d2 = (const float2*)(flat_s + (size_t)b * NFLAT);
  for (int i = tid; i < NFLAT / 2; i += 256) {
    float2 v = d2[i];
    sdata[2 * i] = v.x; sdata[2 * i + 1] = v.y;
  }
  __syncthreads();
  auto getv = [&](int i) -> float { return sdata[i]; };
  u32 V; int GT, r;
  radix_select(getv, NFLAT, MAXDET, hist, suf, sh2, tid, V, GT, r);
  if (tid == 0) { cgt = 0; ctie = 0; }
  __syncthreads();
  for (int i = tid; i < NFLAT; i += 256) {
    u32 u = __float_as_uint(sdata[i]);
    if (u > V) {
      int p = atomicAdd(&cgt, 1);
      sel[p] = ((u64)u << 32) | (u32)(~(u32)i);
    } else if (u == V) {
      int p = atomicAdd(&ctie, 1);
      if (p < 256) tie[p] = (u32)i;
    }
  }
  __syncthreads();
  int nt = ctie < 256 ? ctie : 256;
  for (int i = tid + nt; i < 256; i += 256) tie[i] = 0xFFFFFFFFu;
  __syncthreads();
  bitonic_u32_asc(tie, 256, tid);
  for (int i = tid; i < r; i += 256)
    sel[GT + i] = ((u64)V << 32) | (u32)(~tie[i]);
  for (int i = MAXDET + tid; i < 128; i += 256) sel[i] = 0;
  __syncthreads();
  bitonic_u64_asc(sel, 128, tid);
  for (int d = tid; d < MAXDET; d += 256) {
    u64 kk = sel[127 - d];
    u32 u  = (u32)(kk >> 32);
    int fi = (int)(~(u32)kk);
    float4 bb = ((const float4*)flat_b)[(size_t)b * NFLAT + fi];
    float* o = out + ((size_t)b * MAXDET + d) * 6;
    o[0] = bb.x; o[1] = bb.y; o[2] = bb.z; o[3] = bb.w;
    o[4] = (float)(fi / 100 + 1);
    o[5] = __uint_as_float(u);
  }
}

// ---------------- launch ----------------
extern "C" void kernel_launch(void* const* d_in, const int* in_sizes, int n_in,
                              void* d_out, int out_size, void* d_ws, size_t ws_size,
                              hipStream_t stream) {
  const float* enc    = (const float*)d_in[0];
  const float* logits = (const float*)d_in[1];
  const float* anch   = (const float*)d_in[2];
  float* out = (float*)d_out;
  char* ws = (char*)d_ws;

  size_t off = 0;
  auto alloc = [&](size_t bytes) {
    size_t o = off;
    off += (bytes + 255) & ~(size_t)255;
    return o;
  };
  size_t o_tks  = alloc((size_t)NROWS * KSEL * 4);
  size_t o_tki  = alloc((size_t)NROWS * KSEL * 4);
  size_t o_fls  = alloc((size_t)BB * NFLAT * 4);
  size_t o_flb  = alloc((size_t)BB * NFLAT * 16);
  size_t need_base = off;
  size_t o_sc = off;                                   // chunked sc goes here
  size_t per_batch_sc = ((size_t)NCLS * AA * 4 + 255) & ~(size_t)255; // 6.92 MB

  int CB = 0;
  for (int cb = BB; cb >= 1; cb >>= 1) {
    if (ws_size >= need_base + (size_t)cb * per_batch_sc) { CB = cb; break; }
  }

  float* tks = (float*)(ws + o_tks);
  int*   tki = (int*)  (ws + o_tki);
  float* fls = (float*)(ws + o_fls);
  float* flb = (float*)(ws + o_flb);
  float* scp = (float*)(ws + o_sc);

  if (CB > 0) {
    for (int b0 = 0; b0 < BB; b0 += CB) {
      hipLaunchKernelGGL(k_sigT, dim3((AA + ATILE - 1) / ATILE, CB), dim3(256), 0,
                         stream, logits, scp, b0);
      hipLaunchKernelGGL(k_row, dim3(NCLS * CB), dim3(512), 0, stream,
                         scp, tks, tki, b0 * NCLS);
    }
  } else {
    hipLaunchKernelGGL(k_topk_direct, dim3(NROWS), dim3(256), 0, stream,
                       logits, tks, tki);
  }
  hipLaunchKernelGGL(k_nms, dim3(NROWS / 4), dim3(256), 0, stream,
                     enc, anch, tks, tki, fls, flb);
  hipLaunchKernelGGL(k_final, dim3(BB), dim3(256), 0, stream,
                     fls, flb, out);
}